// Round 1
// baseline (396.431 us; speedup 1.0000x reference)
//
#include <hip/hip_runtime.h>
#include <math.h>

// ---------------------------------------------------------------------------
// CSDM pipeline on MI355X. fp32 in/out, fp32/bf16 intermediates in d_ws.
// B=4, C=32, H=W=256. MFMA head conv; bf16 channel-last gather sources
// (16B load = 8 channels); batched gather loads (16 in flight); channel
// means fused into producer kernels (no mean pass).
// Layout law (r6): bulk WRITES plane-major dense; gather READS channel-last.
// r7: head kernel split per-head across blockIdx.z (2048 blocks), LDS
// union (tile reused for hidw/ysum -> 20.7KB), butterfly-split mean reduce.
// ---------------------------------------------------------------------------

constexpr int B = 4, C = 32, H = 256, W = 256;
constexpr int HW = H * W;
constexpr int H1 = 128, W1 = 128, HW1 = H1 * W1;
constexpr int H2 = 64,  W2 = 64,  HW2 = H2 * W2;
constexpr int CH = 16;   // head hidden channels
constexpr int CO = 12;   // head output channels
constexpr int TILE = 16;
constexpr int HALO = 18;
constexpr int TAREA = HALO * HALO;   // 324
constexpr int WP = 258;              // padded q edge

typedef unsigned short ushort_t;
typedef __attribute__((ext_vector_type(8))) short bf16x8;
typedef __attribute__((ext_vector_type(4))) float f32x4;
typedef __attribute__((ext_vector_type(2))) float v2f;

static __device__ __forceinline__ float fast_rcp(float x) { return __builtin_amdgcn_rcpf(x); }
static __device__ __forceinline__ float silu_f(float x) { return x * fast_rcp(1.0f + __expf(-x)); }
static __device__ __forceinline__ v2f silu2(v2f x) {
    v2f r; r.x = silu_f(x.x); r.y = silu_f(x.y); return r;
}
static __device__ __forceinline__ float tanh_f(float x) {
    float xc = fminf(fmaxf(x, -15.0f), 15.0f);
    float e = __expf(2.0f * xc);
    return (e - 1.0f) * fast_rcp(e + 1.0f);
}
static __device__ __forceinline__ ushort_t f2b(float f) {   // fp32 -> bf16 RNE
    unsigned u = __float_as_uint(f);
    return (ushort_t)((u + 0x7fffu + ((u >> 16) & 1u)) >> 16);
}
static __device__ __forceinline__ float bl(unsigned u) { return __uint_as_float(u << 16); }
static __device__ __forceinline__ float bh(unsigned u) { return __uint_as_float(u & 0xffff0000u); }
static __device__ __forceinline__ float wave_sum(float s) {
    s += __shfl_xor(s, 32, 64); s += __shfl_xor(s, 16, 64);
    s += __shfl_xor(s, 8, 64);  s += __shfl_xor(s, 4, 64);
    s += __shfl_xor(s, 2, 64);  s += __shfl_xor(s, 1, 64);
    return s;
}

// Multi-value butterfly: 8 per-thread channel values -> full-wave sum of
// channel c(lane)=4*b0+2*b1+b2 in lane. 10 shuffles vs 48 for 8 wave_sums.
static __device__ __forceinline__ float red8_ch(float v0, float v1, float v2, float v3,
                                                float v4, float v5, float v6, float v7,
                                                int lane) {
    bool q0 = (lane & 1) != 0, q1 = (lane & 2) != 0, q2 = (lane & 4) != 0;
    float a0 = (q0 ? v4 : v0) + __shfl_xor(q0 ? v0 : v4, 1, 64);
    float a1 = (q0 ? v5 : v1) + __shfl_xor(q0 ? v1 : v5, 1, 64);
    float a2 = (q0 ? v6 : v2) + __shfl_xor(q0 ? v2 : v6, 1, 64);
    float a3 = (q0 ? v7 : v3) + __shfl_xor(q0 ? v3 : v7, 1, 64);
    float c0 = (q1 ? a2 : a0) + __shfl_xor(q1 ? a0 : a2, 2, 64);
    float c1 = (q1 ? a3 : a1) + __shfl_xor(q1 ? a1 : a3, 2, 64);
    float e  = (q2 ? c1 : c0) + __shfl_xor(q2 ? c0 : c1, 4, 64);
    e += __shfl_xor(e, 8, 64);
    e += __shfl_xor(e, 16, 64);
    e += __shfl_xor(e, 32, 64);
    return e;
}

// ---- pre: pool2 + qpad border + dall zero + w1 bf16 reorder ---------------
__global__ void pre_kernel(const float* __restrict__ x, float* __restrict__ s1,
                           ushort_t* __restrict__ qpad, float* __restrict__ dall,
                           const float* __restrict__ h1w1, const float* __restrict__ h2w1,
                           ushort_t* __restrict__ w1ra, ushort_t* __restrict__ w1rb) {
    int idx = blockIdx.x * blockDim.x + threadIdx.x;
    constexpr int NP = B * C * HW1;
    if (idx < NP) {
        int wo = idx % W1; int t = idx / W1;
        int ho = t % H1;   t /= H1;
        const float* src = x + ((size_t)t * H + (size_t)ho * 2) * W + (size_t)wo * 2;
        s1[idx] = (src[0] + src[1] + src[W] + src[W + 1]) * 0.25f;
        return;
    }
    int i = idx - NP;
    if (i < 4112) {                       // qpad border (4*1028)
        int b = i / 1028, r = i % 1028;
        int y, xx;
        if (r < 258)      { y = 0;           xx = r; }
        else if (r < 516) { y = 257;         xx = r - 258; }
        else if (r < 772) { y = r - 516 + 1; xx = 0; }
        else              { y = r - 772 + 1; xx = 257; }
        uint4 z4 = {0, 0, 0, 0};
        uint4* p = (uint4*)(qpad + (((size_t)b * WP + y) * WP + xx) * 32);
        p[0] = z4; p[1] = z4; p[2] = z4; p[3] = z4;
        return;
    }
    i -= 4112;
    if (i < 512) { dall[i] = 0.0f; return; }
    i -= 512;
    if (i < 4608) {                       // w1ra[o*288 + tap*32 + ci]
        int o = i / 288, k = i - o * 288;
        int j = k >> 5, ci = k & 31;
        w1ra[i] = f2b(h1w1[(o * C + ci) * 9 + j]);
        return;
    }
    i -= 4608;
    if (i < 4608) {
        int o = i / 288, k = i - o * 288;
        int j = k >> 5, ci = k & 31;
        w1rb[i] = f2b(h2w1[(o * C + ci) * 9 + j]);
    }
}

// ---- pool by 2 (s1 -> s2) -------------------------------------------------
__global__ void pool4_kernel(const float* __restrict__ s1, float* __restrict__ s2) {
    int idx = blockIdx.x * blockDim.x + threadIdx.x;
    if (idx >= B * C * HW2) return;
    int wo = idx % W2; int t = idx / W2;
    int ho = t % H2;   t /= H2;
    const float* src = s1 + ((size_t)t * H1 + (size_t)ho * 2) * W1 + (size_t)wo * 2;
    s2[idx] = (src[0] + src[1] + src[W1] + src[W1 + 1]) * 0.25f;
}

// ---- fused ds_block: dwconv3 + 1x1 + BN + SiLU, packed f32 ----------------
// CHLAST: bf16 channel-last [b][p][c] (gather source). Else fp32 plane,
// plus q-proj (bf16 padded channel-last) and z0 channel-mean atomics.
template<bool CHLAST>
__global__ __launch_bounds__(256, 4) void fused_ds_kernel(
        const float* __restrict__ in, const float* __restrict__ dw,
        const float* __restrict__ pw, const float* __restrict__ g,
        const float* __restrict__ bb, const float* __restrict__ m,
        const float* __restrict__ v, const float* __restrict__ qw,
        float* __restrict__ out, ushort_t* __restrict__ outcl,
        ushort_t* __restrict__ qout, float* __restrict__ dall,
        int Hs, int Ws, int tilesX) {
    __shared__ unsigned tileu[16 * TAREA];     // 2-ch interleaved bf16, 20736 B
    __shared__ v2f dwp[16 * 9];
    __shared__ v2f pwp[C * 16];                // pwp[ci*16+o2] = {w[2o2][ci], w[2o2+1][ci]}
    __shared__ v2f qwp[CHLAST ? 1 : C * 16];
    __shared__ v2f scale2[16], shift2[16];
    __shared__ float zsum[CHLAST ? 1 : 4][CHLAST ? 1 : 32];
    int tid = threadIdx.x;
    int b = blockIdx.y;
    int HWs = Hs * Ws;
    int ox = (blockIdx.x % tilesX) * TILE;
    int oy = (blockIdx.x / tilesX) * TILE;

    for (int i = tid; i < 16 * 9; i += 256) {
        int c2 = i / 9, j = i - c2 * 9;
        dwp[i] = (v2f){dw[(2 * c2) * 9 + j], dw[(2 * c2 + 1) * 9 + j]};
    }
    for (int i = tid; i < C * 16; i += 256) {
        int ci = i >> 4, o2 = i & 15;
        pwp[i] = (v2f){pw[(2 * o2) * C + ci], pw[(2 * o2 + 1) * C + ci]};
        if (!CHLAST) qwp[i] = (v2f){qw[(2 * o2) * C + ci], qw[(2 * o2 + 1) * C + ci]};
    }
    if (tid < 16) {
        float s0 = g[2 * tid] * rsqrtf(v[2 * tid] + 1e-5f);
        float s1v = g[2 * tid + 1] * rsqrtf(v[2 * tid + 1] + 1e-5f);
        scale2[tid] = (v2f){s0, s1v};
        shift2[tid] = (v2f){bb[2 * tid] - m[2 * tid] * s0, bb[2 * tid + 1] - m[2 * tid + 1] * s1v};
    }
    const float* src = in + (size_t)b * C * HWs;
    for (int i = tid; i < 16 * TAREA; i += 256) {
        int c2 = i / TAREA, r = i - c2 * TAREA;
        int yy = r / HALO, xx = r - yy * HALO;
        int gy = oy - 1 + yy, gx = ox - 1 + xx;
        float v0 = 0.0f, v1 = 0.0f;
        if (gy >= 0 && gy < Hs && gx >= 0 && gx < Ws) {
            const float* sp = src + (size_t)(2 * c2) * HWs + gy * Ws + gx;
            v0 = sp[0]; v1 = sp[HWs];
        }
        tileu[i] = (unsigned)f2b(v0) | ((unsigned)f2b(v1) << 16);
    }
    __syncthreads();

    int tx = tid & 15, ty = tid >> 4;
    int off[9];
#pragma unroll
    for (int jy = 0; jy < 3; ++jy)
#pragma unroll
        for (int jx = 0; jx < 3; ++jx)
            off[jy * 3 + jx] = (ty + jy) * HALO + tx + jx;

    v2f t2[16];
#pragma unroll
    for (int c2 = 0; c2 < 16; ++c2) {
        v2f s = {0.0f, 0.0f};
        const unsigned* tp = tileu + c2 * TAREA;
#pragma unroll
        for (int j = 0; j < 9; ++j) {
            unsigned u = tp[off[j]];
            v2f val = {bl(u), bh(u)};
            s += dwp[c2 * 9 + j] * val;
        }
        t2[c2] = s;
    }

    v2f acc2[16];
#pragma unroll
    for (int o2 = 0; o2 < 16; ++o2) acc2[o2] = (v2f){0.0f, 0.0f};
#pragma unroll
    for (int i2 = 0; i2 < 16; ++i2) {
        float ta = t2[i2].x, tb = t2[i2].y;
        const v2f* r0 = pwp + (2 * i2) * 16;
        const v2f* r1 = r0 + 16;
#pragma unroll
        for (int o2 = 0; o2 < 16; ++o2)
            acc2[o2] += r0[o2] * ta + r1[o2] * tb;
    }
#pragma unroll
    for (int o2 = 0; o2 < 16; ++o2)
        acc2[o2] = silu2(acc2[o2] * scale2[o2] + shift2[o2]);

    int px = ox + tx, py = oy + ty;
    int p = py * Ws + px;
    if (CHLAST) {
        // bf16 channel-last: 32 ch -> 16 uints -> 4 uint4 stores (64 B/px)
        unsigned up[16];
#pragma unroll
        for (int j = 0; j < 16; ++j)
            up[j] = (unsigned)f2b(acc2[j].x) | ((unsigned)f2b(acc2[j].y) << 16);
        uint4* dst = (uint4*)(outcl + ((size_t)b * HWs + p) * C);
#pragma unroll
        for (int j = 0; j < 4; ++j)
            dst[j] = make_uint4(up[4 * j], up[4 * j + 1], up[4 * j + 2], up[4 * j + 3]);
    } else {
        float* dst = out + (size_t)b * C * HWs + p;
#pragma unroll
        for (int o2 = 0; o2 < 16; ++o2) {
            dst[(size_t)(2 * o2) * HWs] = acc2[o2].x;
            dst[(size_t)(2 * o2 + 1) * HWs] = acc2[o2].y;
        }
        // q projection -> bf16 padded channel-last
        v2f q2[16];
#pragma unroll
        for (int o2 = 0; o2 < 16; ++o2) q2[o2] = (v2f){0.0f, 0.0f};
#pragma unroll
        for (int i2 = 0; i2 < 16; ++i2) {
            float ta = acc2[i2].x, tb = acc2[i2].y;
            const v2f* r0 = qwp + (2 * i2) * 16;
            const v2f* r1 = r0 + 16;
#pragma unroll
            for (int o2 = 0; o2 < 16; ++o2)
                q2[o2] += r0[o2] * ta + r1[o2] * tb;
        }
        unsigned up[16];
#pragma unroll
        for (int j = 0; j < 16; ++j)
            up[j] = (unsigned)f2b(q2[j].x) | ((unsigned)f2b(q2[j].y) << 16);
        uint4* qd = (uint4*)(qout + (((size_t)b * WP + py + 1) * WP + px + 1) * 32);
#pragma unroll
        for (int j = 0; j < 4; ++j)
            qd[j] = make_uint4(up[4 * j], up[4 * j + 1], up[4 * j + 2], up[4 * j + 3]);
        // z0 channel means (wave shuffle reduce + atomics)
        int lane = tid & 63, wv = tid >> 6;
#pragma unroll
        for (int o2 = 0; o2 < 16; ++o2) {
            float sx = wave_sum(acc2[o2].x);
            float sy = wave_sum(acc2[o2].y);
            if (lane == 0) { zsum[wv][2 * o2] = sx; zsum[wv][2 * o2 + 1] = sy; }
        }
        __syncthreads();
        if (tid < 32)
            atomicAdd(&dall[b * 96 + tid],
                      (zsum[0][tid] + zsum[1][tid] + zsum[2][tid] + zsum[3][tid]) * (1.0f / HW));
    }
}

// ---- offsets/weights for one head (halfword offsets into bf16 z) ----------
template<int HC, int WC>
static __device__ __forceinline__ void calc_off(const float* o12, int px, int py,
                                                int* zoff, float* wgt) {
    float mx = fmaxf(fmaxf(o12[8], o12[9]), fmaxf(o12[10], o12[11]));
    float e0 = __expf(o12[8] - mx), e1 = __expf(o12[9] - mx);
    float e2 = __expf(o12[10] - mx), e3 = __expf(o12[11] - mx);
    float inv = fast_rcp(e0 + e1 + e2 + e3);
    float wk4[4] = {e0 * inv, e1 * inv, e2 * inv, e3 * inv};
    float xc = (px + 0.5f) * ((float)WC / (float)W) - 0.5f;
    float yc = (py + 0.5f) * ((float)HC / (float)H) - 0.5f;
#pragma unroll
    for (int k = 0; k < 4; ++k) {
        float ix = fminf(fmaxf(xc + 2.0f * tanh_f(o12[2 * k]),     0.0f), (float)(WC - 1));
        float iy = fminf(fmaxf(yc + 2.0f * tanh_f(o12[2 * k + 1]), 0.0f), (float)(HC - 1));
        float x0f = floorf(ix), y0f = floorf(iy);
        int x0 = (int)x0f, y0 = (int)y0f;
        int x1 = min(x0 + 1, WC - 1), y1 = min(y0 + 1, HC - 1);
        float wx = ix - x0f, wy = iy - y0f;
        float wk = wk4[k];
        zoff[4 * k + 0] = (y0 * WC + x0) * C; wgt[4 * k + 0] = (1.0f - wx) * (1.0f - wy) * wk;
        zoff[4 * k + 1] = (y0 * WC + x1) * C; wgt[4 * k + 1] = wx * (1.0f - wy) * wk;
        zoff[4 * k + 2] = (y1 * WC + x0) * C; wgt[4 * k + 2] = (1.0f - wx) * wy * wk;
        zoff[4 * k + 3] = (y1 * WC + x1) * C; wgt[4 * k + 3] = wx * wy * wk;
    }
}

// ---- one head per block (blockIdx.z): MFMA 3x3 conv + gather tail + means -
// LDS union: q tile (20736 B) is dead after the MFMA loop; hidw (9216 B)
// and ysum (512 B) reuse it -> 20.7 KB/block, 6-7 blocks/CU resident.
__global__ __launch_bounds__(256, 6) void head_deform_kernel(
        const ushort_t* __restrict__ qpad,
        const ushort_t* __restrict__ z1, const ushort_t* __restrict__ z2,
        const ushort_t* __restrict__ w1ra, const ushort_t* __restrict__ w1rb,
        const float* __restrict__ w2a, const float* __restrict__ b2a,
        const float* __restrict__ w2b, const float* __restrict__ b2b,
        float* __restrict__ y1, float* __restrict__ y2, float* __restrict__ dall) {
    __shared__ __align__(16) char smem[TAREA * C * 2];      // 20736 B
    ushort_t* tile = (ushort_t*)smem;
    unsigned* hidw = (unsigned*)smem;                       // bytes [0, 9216)
    float (*ysum)[32] = (float (*)[32])(smem + 9216);       // bytes [9216, 9728)
    int tid = threadIdx.x, b = blockIdx.y, hsel = blockIdx.z;
    int ox = (blockIdx.x & 15) * TILE, oy = (blockIdx.x >> 4) * TILE;
    int lane = tid & 63, wv = tid >> 6;
    int n15 = lane & 15, quad = lane >> 4;
    int tx = tid & 15, ty = tid >> 4;

    // stage q tile (rows contiguous in padded channel-last q)
    {
        const ushort_t* base = qpad + ((size_t)b * WP + oy) * WP * 32;
        uint4* tl = (uint4*)tile;
        for (int i = tid; i < 1296; i += 256) {      // 18 rows * 72 16B-chunks
            int yy = i / 72, r = i - yy * 72;
            tl[i] = *(const uint4*)(base + ((size_t)yy * WP + ox) * 32 + r * 8);
        }
    }
    __syncthreads();

    const ushort_t* w1r = hsel ? w1rb : w1ra;
    bf16x8 af[9];
#pragma unroll
    for (int j = 0; j < 9; ++j)
        af[j] = *(const bf16x8*)(w1r + n15 * 288 + j * 32 + quad * 8);
    unsigned pk[8];
#pragma unroll
    for (int g = 0; g < 4; ++g) {
        int yrow = wv * 4 + g;
        f32x4 acc = {0.0f, 0.0f, 0.0f, 0.0f};
#pragma unroll
        for (int jy = 0; jy < 3; ++jy)
#pragma unroll
            for (int jx = 0; jx < 3; ++jx) {
                const bf16x8* bp = (const bf16x8*)(tile +
                    ((yrow + jy) * HALO + n15 + jx) * 32 + quad * 8);
                acc = __builtin_amdgcn_mfma_f32_16x16x32_bf16(
                    af[jy * 3 + jx], *bp, acc, 0, 0, 0);
            }
        pk[2 * g]     = (unsigned)f2b(acc[0]) | ((unsigned)f2b(acc[1]) << 16);
        pk[2 * g + 1] = (unsigned)f2b(acc[2]) | ((unsigned)f2b(acc[3]) << 16);
    }
    __syncthreads();   // ALL waves done reading tile before hidw overwrites it
#pragma unroll
    for (int g = 0; g < 4; ++g) {
        int pxl = (wv * 4 + g) * 16 + n15;
        hidw[pxl * 9 + quad * 2]     = pk[2 * g];
        hidw[pxl * 9 + quad * 2 + 1] = pk[2 * g + 1];
    }
    // hidw write->read is same-wave (pxl in [wv*64, wv*64+64)); lgkmcnt covers it
    float hid[CH];
#pragma unroll
    for (int j = 0; j < 8; ++j) {
        unsigned u = hidw[tid * 9 + j];
        hid[2 * j]     = silu_f(bl(u));
        hid[2 * j + 1] = silu_f(bh(u));
    }

    // ---- tail for this head ----
    const float* w2 = hsel ? w2b : w2a;
    const float* bs = hsel ? b2b : b2a;
    float o12[CO];
#pragma unroll
    for (int j = 0; j < CO; ++j) {
        float a = bs[j];
#pragma unroll
        for (int i = 0; i < CH; ++i) a += w2[j * CH + i] * hid[i];
        o12[j] = a;
    }
    int px = ox + tx, py = oy + ty;
    int off[16]; float wg[16];
    if (hsel == 0) calc_off<H1, W1>(o12, px, py, off, wg);
    else           calc_off<H2, W2>(o12, px, py, off, wg);

    const ushort_t* zb = hsel ? z2 + (size_t)b * HW2 * C : z1 + (size_t)b * HW1 * C;
    int p = py * W + px;
    float* d = (hsel ? y2 : y1) + (size_t)b * C * HW + p;

#pragma unroll
    for (int c8 = 0; c8 < 4; ++c8) {
        uint4 vv[16];
#pragma unroll
        for (int j = 0; j < 16; ++j)
            vv[j] = *(const uint4*)(zb + off[j] + c8 * 8);
        f32x4 lo = {0.0f, 0.0f, 0.0f, 0.0f};
        f32x4 hi = {0.0f, 0.0f, 0.0f, 0.0f};
#pragma unroll
        for (int j = 0; j < 16; ++j) {
            float wj = wg[j];
            lo[0] += wj * bl(vv[j].x); lo[1] += wj * bh(vv[j].x);
            lo[2] += wj * bl(vv[j].y); lo[3] += wj * bh(vv[j].y);
            hi[0] += wj * bl(vv[j].z); hi[1] += wj * bh(vv[j].z);
            hi[2] += wj * bl(vv[j].w); hi[3] += wj * bh(vv[j].w);
        }
#pragma unroll
        for (int k = 0; k < 4; ++k) {
            d[(size_t)(c8 * 8 + k) * HW]     = lo[k];
            d[(size_t)(c8 * 8 + 4 + k) * HW] = hi[k];
        }
        // channel means: butterfly-split reduce (10 shuffles for 8 channels)
        float s = red8_ch(lo[0], lo[1], lo[2], lo[3], hi[0], hi[1], hi[2], hi[3], lane);
        if (lane < 8)
            ysum[wv][c8 * 8 + ((lane & 1) * 4 + (lane & 2) + ((lane >> 2) & 1))] = s;
    }
    __syncthreads();
    if (tid < 32) {
        float s = ysum[0][tid] + ysum[1][tid] + ysum[2][tid] + ysum[3][tid];
        atomicAdd(&dall[b * 96 + 32 + hsel * 32 + tid], s * (1.0f / HW));
    }
}

// ---- gating MLP + softmax -> alpha[B*3] -----------------------------------
__global__ void gate_kernel(const float* __restrict__ dall,
                            const float* __restrict__ w1, const float* __restrict__ b1,
                            const float* __restrict__ w2, const float* __restrict__ b2,
                            float* __restrict__ alpha) {
    __shared__ float hid[B][32];
    int tid = threadIdx.x;
    int b = tid >> 5, j = tid & 31;
    float a = b1[j];
    for (int k = 0; k < 96; ++k) a += dall[b * 96 + k] * w1[k * 32 + j];
    hid[b][j] = silu_f(a);
    __syncthreads();
    if (j == 0) {
        float lg[3];
#pragma unroll
        for (int t = 0; t < 3; ++t) {
            float acc = b2[t];
            for (int jj = 0; jj < 32; ++jj) acc += hid[b][jj] * w2[jj * 3 + t];
            lg[t] = acc;
        }
        float mx = fmaxf(lg[0], fmaxf(lg[1], lg[2]));
        float e0 = __expf(lg[0] - mx), e1 = __expf(lg[1] - mx), e2 = __expf(lg[2] - mx);
        float inv = fast_rcp(e0 + e1 + e2);
        alpha[b * 3 + 0] = e0 * inv;
        alpha[b * 3 + 1] = e1 * inv;
        alpha[b * 3 + 2] = e2 * inv;
    }
}

// ---- fused mix + final 1x1 conv + residual (2 pixels/thread, packed) ------
__global__ __launch_bounds__(256, 4) void final_kernel(
        const float* __restrict__ x,
        const float* __restrict__ z0, const float* __restrict__ y1,
        const float* __restrict__ y2, const float* __restrict__ alpha,
        const float* __restrict__ fw, float* __restrict__ out) {
    __shared__ float ws[C * C];
    for (int i = threadIdx.x; i < C * C; i += blockDim.x) ws[i] = fw[i];
    __syncthreads();
    int idx = blockIdx.x * blockDim.x + threadIdx.x;
    constexpr int HP = HW / 2;
    if (idx >= B * HP) return;
    int b = idx / HP, p = (idx - b * HP) * 2;
    float a0 = alpha[b * 3], a1 = alpha[b * 3 + 1], a2 = alpha[b * 3 + 2];
    size_t base = (size_t)b * C * HW + p;
    v2f mix[C];
#pragma unroll
    for (int i = 0; i < C; ++i) {
        size_t e = base + (size_t)i * HW;
        v2f za = *(const v2f*)(z0 + e);
        v2f ya = *(const v2f*)(y1 + e);
        v2f yb = *(const v2f*)(y2 + e);
        mix[i] = a0 * za + a1 * ya + a2 * yb;
    }
#pragma unroll 4
    for (int o = 0; o < C; ++o) {
        v2f acc = {0.0f, 0.0f};
#pragma unroll
        for (int i = 0; i < C; ++i) acc += ws[o * C + i] * mix[i];
        size_t e = base + (size_t)o * HW;
        v2f xr = *(const v2f*)(x + e);
        *(v2f*)(out + e) = acc + xr;
    }
}

// ---------------------------------------------------------------------------
extern "C" void kernel_launch(void* const* d_in, const int* in_sizes, int n_in,
                              void* d_out, int out_size, void* d_ws, size_t ws_size,
                              hipStream_t stream) {
    const float* x       = (const float*)d_in[0];
    const float* ds_dw[3] = {(const float*)d_in[1],  (const float*)d_in[7],  (const float*)d_in[13]};
    const float* ds_pw[3] = {(const float*)d_in[2],  (const float*)d_in[8],  (const float*)d_in[14]};
    const float* ds_g[3]  = {(const float*)d_in[3],  (const float*)d_in[9],  (const float*)d_in[15]};
    const float* ds_b[3]  = {(const float*)d_in[4],  (const float*)d_in[10], (const float*)d_in[16]};
    const float* ds_m[3]  = {(const float*)d_in[5],  (const float*)d_in[11], (const float*)d_in[17]};
    const float* ds_v[3]  = {(const float*)d_in[6],  (const float*)d_in[12], (const float*)d_in[18]};
    const float* qproj_w = (const float*)d_in[19];
    const float* h1_w1   = (const float*)d_in[20];
    const float* h1_w2   = (const float*)d_in[21];
    const float* h1_b2   = (const float*)d_in[22];
    const float* h2_w1   = (const float*)d_in[23];
    const float* h2_w2   = (const float*)d_in[24];
    const float* h2_b2   = (const float*)d_in[25];
    const float* r_w1    = (const float*)d_in[26];
    const float* r_b1    = (const float*)d_in[27];
    const float* r_w2    = (const float*)d_in[28];
    const float* r_b2    = (const float*)d_in[29];
    const float* final_w = (const float*)d_in[30];
    float* out = (float*)d_out;

    constexpr size_t N0 = (size_t)B * C * HW;
    constexpr size_t N1 = (size_t)B * C * HW1;
    constexpr size_t N2 = (size_t)B * C * HW2;
    constexpr size_t NQ = ((size_t)B * WP * WP * 32 + 1) / 2;   // qpad (u16) in floats

    float* w = (float*)d_ws;
    float* z0   = w; w += N0;      // plane fp32
    float* y1   = w; w += N0;      // plane fp32
    float* y2   = w; w += N0;      // plane fp32
    ushort_t* z1cl = (ushort_t*)w; w += N1 / 2;   // bf16 channel-last
    ushort_t* z2cl = (ushort_t*)w; w += N2 / 2;   // bf16 channel-last
    float* s1   = w; w += N1;
    float* s2   = w; w += N2;
    ushort_t* qpad = (ushort_t*)w; w += NQ;
    ushort_t* w1ra = (ushort_t*)w; w += 2304;   // 4608 bf16
    ushort_t* w1rb = (ushort_t*)w; w += 2304;
    float* dall  = w; w += 512;
    float* alpha = w; w += 16;
    (void)ws_size; (void)in_sizes; (void)n_in; (void)out_size;

    const int T = 256;
    auto g = [](size_t n, int t) { return (int)((n + t - 1) / t); };

    pre_kernel<<<g(N1 + 4112 + 512 + 9216, T), T, 0, stream>>>(
        x, s1, qpad, dall, h1_w1, h2_w1, w1ra, w1rb);
    pool4_kernel<<<g(N2, T), T, 0, stream>>>(s1, s2);

    fused_ds_kernel<false><<<dim3((H / TILE) * (W / TILE), B), T, 0, stream>>>(
        x, ds_dw[0], ds_pw[0], ds_g[0], ds_b[0], ds_m[0], ds_v[0], qproj_w,
        z0, nullptr, qpad, dall, H, W, W / TILE);
    fused_ds_kernel<true><<<dim3((H1 / TILE) * (W1 / TILE), B), T, 0, stream>>>(
        s1, ds_dw[1], ds_pw[1], ds_g[1], ds_b[1], ds_m[1], ds_v[1], nullptr,
        nullptr, z1cl, nullptr, nullptr, H1, W1, W1 / TILE);
    fused_ds_kernel<true><<<dim3((H2 / TILE) * (W2 / TILE), B), T, 0, stream>>>(
        s2, ds_dw[2], ds_pw[2], ds_g[2], ds_b[2], ds_m[2], ds_v[2], nullptr,
        nullptr, z2cl, nullptr, nullptr, H2, W2, W2 / TILE);

    head_deform_kernel<<<dim3((H / TILE) * (W / TILE), B, 2), T, 0, stream>>>(
        qpad, z1cl, z2cl, w1ra, w1rb, h1_w2, h1_b2, h2_w2, h2_b2, y1, y2, dall);

    gate_kernel<<<1, 128, 0, stream>>>(dall, r_w1, r_b1, r_w2, r_b2, alpha);

    final_kernel<<<g((size_t)B * HW / 2, T), T, 0, stream>>>(x, z0, y1, y2, alpha, final_w, out);
}

// Round 2
// 327.340 us; speedup vs baseline: 1.2111x; 1.2111x over previous
//
#include <hip/hip_runtime.h>
#include <math.h>

// ---------------------------------------------------------------------------
// CSDM pipeline on MI355X. fp32 in/out, fp32/bf16 intermediates in d_ws.
// B=4, C=32, H=W=256. MFMA head conv; bf16 channel-last gather sources
// (16B load = 8 channels); batched gather loads (16 in flight); channel
// means fused into producer kernels (no mean pass).
// Layout law (r6): bulk WRITES plane-major dense; gather READS channel-last.
// r7: head kernel split per-head across blockIdx.z (2048 blocks), LDS
// union (tile reused for hidw/ysum -> 20.7KB), butterfly-split mean reduce.
// r8: launch_bounds 6->4. (256,6) forced VGPR=40 -> scratch spill of the
// 16-deep gather batch (+88MB FETCH & +88MB WRITE, matched = spill
// signature). 128-VGPR budget holds vv[16]+off+wg+af with zero spills.
// ---------------------------------------------------------------------------

constexpr int B = 4, C = 32, H = 256, W = 256;
constexpr int HW = H * W;
constexpr int H1 = 128, W1 = 128, HW1 = H1 * W1;
constexpr int H2 = 64,  W2 = 64,  HW2 = H2 * W2;
constexpr int CH = 16;   // head hidden channels
constexpr int CO = 12;   // head output channels
constexpr int TILE = 16;
constexpr int HALO = 18;
constexpr int TAREA = HALO * HALO;   // 324
constexpr int WP = 258;              // padded q edge

typedef unsigned short ushort_t;
typedef __attribute__((ext_vector_type(8))) short bf16x8;
typedef __attribute__((ext_vector_type(4))) float f32x4;
typedef __attribute__((ext_vector_type(2))) float v2f;

static __device__ __forceinline__ float fast_rcp(float x) { return __builtin_amdgcn_rcpf(x); }
static __device__ __forceinline__ float silu_f(float x) { return x * fast_rcp(1.0f + __expf(-x)); }
static __device__ __forceinline__ v2f silu2(v2f x) {
    v2f r; r.x = silu_f(x.x); r.y = silu_f(x.y); return r;
}
static __device__ __forceinline__ float tanh_f(float x) {
    float xc = fminf(fmaxf(x, -15.0f), 15.0f);
    float e = __expf(2.0f * xc);
    return (e - 1.0f) * fast_rcp(e + 1.0f);
}
static __device__ __forceinline__ ushort_t f2b(float f) {   // fp32 -> bf16 RNE
    unsigned u = __float_as_uint(f);
    return (ushort_t)((u + 0x7fffu + ((u >> 16) & 1u)) >> 16);
}
static __device__ __forceinline__ float bl(unsigned u) { return __uint_as_float(u << 16); }
static __device__ __forceinline__ float bh(unsigned u) { return __uint_as_float(u & 0xffff0000u); }
static __device__ __forceinline__ float wave_sum(float s) {
    s += __shfl_xor(s, 32, 64); s += __shfl_xor(s, 16, 64);
    s += __shfl_xor(s, 8, 64);  s += __shfl_xor(s, 4, 64);
    s += __shfl_xor(s, 2, 64);  s += __shfl_xor(s, 1, 64);
    return s;
}

// Multi-value butterfly: 8 per-thread channel values -> full-wave sum of
// channel c(lane)=4*b0+2*b1+b2 in lane. 10 shuffles vs 48 for 8 wave_sums.
static __device__ __forceinline__ float red8_ch(float v0, float v1, float v2, float v3,
                                                float v4, float v5, float v6, float v7,
                                                int lane) {
    bool q0 = (lane & 1) != 0, q1 = (lane & 2) != 0, q2 = (lane & 4) != 0;
    float a0 = (q0 ? v4 : v0) + __shfl_xor(q0 ? v0 : v4, 1, 64);
    float a1 = (q0 ? v5 : v1) + __shfl_xor(q0 ? v1 : v5, 1, 64);
    float a2 = (q0 ? v6 : v2) + __shfl_xor(q0 ? v2 : v6, 1, 64);
    float a3 = (q0 ? v7 : v3) + __shfl_xor(q0 ? v3 : v7, 1, 64);
    float c0 = (q1 ? a2 : a0) + __shfl_xor(q1 ? a0 : a2, 2, 64);
    float c1 = (q1 ? a3 : a1) + __shfl_xor(q1 ? a1 : a3, 2, 64);
    float e  = (q2 ? c1 : c0) + __shfl_xor(q2 ? c0 : c1, 4, 64);
    e += __shfl_xor(e, 8, 64);
    e += __shfl_xor(e, 16, 64);
    e += __shfl_xor(e, 32, 64);
    return e;
}

// ---- pre: pool2 + qpad border + dall zero + w1 bf16 reorder ---------------
__global__ void pre_kernel(const float* __restrict__ x, float* __restrict__ s1,
                           ushort_t* __restrict__ qpad, float* __restrict__ dall,
                           const float* __restrict__ h1w1, const float* __restrict__ h2w1,
                           ushort_t* __restrict__ w1ra, ushort_t* __restrict__ w1rb) {
    int idx = blockIdx.x * blockDim.x + threadIdx.x;
    constexpr int NP = B * C * HW1;
    if (idx < NP) {
        int wo = idx % W1; int t = idx / W1;
        int ho = t % H1;   t /= H1;
        const float* src = x + ((size_t)t * H + (size_t)ho * 2) * W + (size_t)wo * 2;
        s1[idx] = (src[0] + src[1] + src[W] + src[W + 1]) * 0.25f;
        return;
    }
    int i = idx - NP;
    if (i < 4112) {                       // qpad border (4*1028)
        int b = i / 1028, r = i % 1028;
        int y, xx;
        if (r < 258)      { y = 0;           xx = r; }
        else if (r < 516) { y = 257;         xx = r - 258; }
        else if (r < 772) { y = r - 516 + 1; xx = 0; }
        else              { y = r - 772 + 1; xx = 257; }
        uint4 z4 = {0, 0, 0, 0};
        uint4* p = (uint4*)(qpad + (((size_t)b * WP + y) * WP + xx) * 32);
        p[0] = z4; p[1] = z4; p[2] = z4; p[3] = z4;
        return;
    }
    i -= 4112;
    if (i < 512) { dall[i] = 0.0f; return; }
    i -= 512;
    if (i < 4608) {                       // w1ra[o*288 + tap*32 + ci]
        int o = i / 288, k = i - o * 288;
        int j = k >> 5, ci = k & 31;
        w1ra[i] = f2b(h1w1[(o * C + ci) * 9 + j]);
        return;
    }
    i -= 4608;
    if (i < 4608) {
        int o = i / 288, k = i - o * 288;
        int j = k >> 5, ci = k & 31;
        w1rb[i] = f2b(h2w1[(o * C + ci) * 9 + j]);
    }
}

// ---- pool by 2 (s1 -> s2) -------------------------------------------------
__global__ void pool4_kernel(const float* __restrict__ s1, float* __restrict__ s2) {
    int idx = blockIdx.x * blockDim.x + threadIdx.x;
    if (idx >= B * C * HW2) return;
    int wo = idx % W2; int t = idx / W2;
    int ho = t % H2;   t /= H2;
    const float* src = s1 + ((size_t)t * H1 + (size_t)ho * 2) * W1 + (size_t)wo * 2;
    s2[idx] = (src[0] + src[1] + src[W1] + src[W1 + 1]) * 0.25f;
}

// ---- fused ds_block: dwconv3 + 1x1 + BN + SiLU, packed f32 ----------------
// CHLAST: bf16 channel-last [b][p][c] (gather source). Else fp32 plane,
// plus q-proj (bf16 padded channel-last) and z0 channel-mean atomics.
template<bool CHLAST>
__global__ __launch_bounds__(256, 4) void fused_ds_kernel(
        const float* __restrict__ in, const float* __restrict__ dw,
        const float* __restrict__ pw, const float* __restrict__ g,
        const float* __restrict__ bb, const float* __restrict__ m,
        const float* __restrict__ v, const float* __restrict__ qw,
        float* __restrict__ out, ushort_t* __restrict__ outcl,
        ushort_t* __restrict__ qout, float* __restrict__ dall,
        int Hs, int Ws, int tilesX) {
    __shared__ unsigned tileu[16 * TAREA];     // 2-ch interleaved bf16, 20736 B
    __shared__ v2f dwp[16 * 9];
    __shared__ v2f pwp[C * 16];                // pwp[ci*16+o2] = {w[2o2][ci], w[2o2+1][ci]}
    __shared__ v2f qwp[CHLAST ? 1 : C * 16];
    __shared__ v2f scale2[16], shift2[16];
    __shared__ float zsum[CHLAST ? 1 : 4][CHLAST ? 1 : 32];
    int tid = threadIdx.x;
    int b = blockIdx.y;
    int HWs = Hs * Ws;
    int ox = (blockIdx.x % tilesX) * TILE;
    int oy = (blockIdx.x / tilesX) * TILE;

    for (int i = tid; i < 16 * 9; i += 256) {
        int c2 = i / 9, j = i - c2 * 9;
        dwp[i] = (v2f){dw[(2 * c2) * 9 + j], dw[(2 * c2 + 1) * 9 + j]};
    }
    for (int i = tid; i < C * 16; i += 256) {
        int ci = i >> 4, o2 = i & 15;
        pwp[i] = (v2f){pw[(2 * o2) * C + ci], pw[(2 * o2 + 1) * C + ci]};
        if (!CHLAST) qwp[i] = (v2f){qw[(2 * o2) * C + ci], qw[(2 * o2 + 1) * C + ci]};
    }
    if (tid < 16) {
        float s0 = g[2 * tid] * rsqrtf(v[2 * tid] + 1e-5f);
        float s1v = g[2 * tid + 1] * rsqrtf(v[2 * tid + 1] + 1e-5f);
        scale2[tid] = (v2f){s0, s1v};
        shift2[tid] = (v2f){bb[2 * tid] - m[2 * tid] * s0, bb[2 * tid + 1] - m[2 * tid + 1] * s1v};
    }
    const float* src = in + (size_t)b * C * HWs;
    for (int i = tid; i < 16 * TAREA; i += 256) {
        int c2 = i / TAREA, r = i - c2 * TAREA;
        int yy = r / HALO, xx = r - yy * HALO;
        int gy = oy - 1 + yy, gx = ox - 1 + xx;
        float v0 = 0.0f, v1 = 0.0f;
        if (gy >= 0 && gy < Hs && gx >= 0 && gx < Ws) {
            const float* sp = src + (size_t)(2 * c2) * HWs + gy * Ws + gx;
            v0 = sp[0]; v1 = sp[HWs];
        }
        tileu[i] = (unsigned)f2b(v0) | ((unsigned)f2b(v1) << 16);
    }
    __syncthreads();

    int tx = tid & 15, ty = tid >> 4;
    int off[9];
#pragma unroll
    for (int jy = 0; jy < 3; ++jy)
#pragma unroll
        for (int jx = 0; jx < 3; ++jx)
            off[jy * 3 + jx] = (ty + jy) * HALO + tx + jx;

    v2f t2[16];
#pragma unroll
    for (int c2 = 0; c2 < 16; ++c2) {
        v2f s = {0.0f, 0.0f};
        const unsigned* tp = tileu + c2 * TAREA;
#pragma unroll
        for (int j = 0; j < 9; ++j) {
            unsigned u = tp[off[j]];
            v2f val = {bl(u), bh(u)};
            s += dwp[c2 * 9 + j] * val;
        }
        t2[c2] = s;
    }

    v2f acc2[16];
#pragma unroll
    for (int o2 = 0; o2 < 16; ++o2) acc2[o2] = (v2f){0.0f, 0.0f};
#pragma unroll
    for (int i2 = 0; i2 < 16; ++i2) {
        float ta = t2[i2].x, tb = t2[i2].y;
        const v2f* r0 = pwp + (2 * i2) * 16;
        const v2f* r1 = r0 + 16;
#pragma unroll
        for (int o2 = 0; o2 < 16; ++o2)
            acc2[o2] += r0[o2] * ta + r1[o2] * tb;
    }
#pragma unroll
    for (int o2 = 0; o2 < 16; ++o2)
        acc2[o2] = silu2(acc2[o2] * scale2[o2] + shift2[o2]);

    int px = ox + tx, py = oy + ty;
    int p = py * Ws + px;
    if (CHLAST) {
        // bf16 channel-last: 32 ch -> 16 uints -> 4 uint4 stores (64 B/px)
        unsigned up[16];
#pragma unroll
        for (int j = 0; j < 16; ++j)
            up[j] = (unsigned)f2b(acc2[j].x) | ((unsigned)f2b(acc2[j].y) << 16);
        uint4* dst = (uint4*)(outcl + ((size_t)b * HWs + p) * C);
#pragma unroll
        for (int j = 0; j < 4; ++j)
            dst[j] = make_uint4(up[4 * j], up[4 * j + 1], up[4 * j + 2], up[4 * j + 3]);
    } else {
        float* dst = out + (size_t)b * C * HWs + p;
#pragma unroll
        for (int o2 = 0; o2 < 16; ++o2) {
            dst[(size_t)(2 * o2) * HWs] = acc2[o2].x;
            dst[(size_t)(2 * o2 + 1) * HWs] = acc2[o2].y;
        }
        // q projection -> bf16 padded channel-last
        v2f q2[16];
#pragma unroll
        for (int o2 = 0; o2 < 16; ++o2) q2[o2] = (v2f){0.0f, 0.0f};
#pragma unroll
        for (int i2 = 0; i2 < 16; ++i2) {
            float ta = acc2[i2].x, tb = acc2[i2].y;
            const v2f* r0 = qwp + (2 * i2) * 16;
            const v2f* r1 = r0 + 16;
#pragma unroll
            for (int o2 = 0; o2 < 16; ++o2)
                q2[o2] += r0[o2] * ta + r1[o2] * tb;
        }
        unsigned up[16];
#pragma unroll
        for (int j = 0; j < 16; ++j)
            up[j] = (unsigned)f2b(q2[j].x) | ((unsigned)f2b(q2[j].y) << 16);
        uint4* qd = (uint4*)(qout + (((size_t)b * WP + py + 1) * WP + px + 1) * 32);
#pragma unroll
        for (int j = 0; j < 4; ++j)
            qd[j] = make_uint4(up[4 * j], up[4 * j + 1], up[4 * j + 2], up[4 * j + 3]);
        // z0 channel means (wave shuffle reduce + atomics)
        int lane = tid & 63, wv = tid >> 6;
#pragma unroll
        for (int o2 = 0; o2 < 16; ++o2) {
            float sx = wave_sum(acc2[o2].x);
            float sy = wave_sum(acc2[o2].y);
            if (lane == 0) { zsum[wv][2 * o2] = sx; zsum[wv][2 * o2 + 1] = sy; }
        }
        __syncthreads();
        if (tid < 32)
            atomicAdd(&dall[b * 96 + tid],
                      (zsum[0][tid] + zsum[1][tid] + zsum[2][tid] + zsum[3][tid]) * (1.0f / HW));
    }
}

// ---- offsets/weights for one head (halfword offsets into bf16 z) ----------
template<int HC, int WC>
static __device__ __forceinline__ void calc_off(const float* o12, int px, int py,
                                                int* zoff, float* wgt) {
    float mx = fmaxf(fmaxf(o12[8], o12[9]), fmaxf(o12[10], o12[11]));
    float e0 = __expf(o12[8] - mx), e1 = __expf(o12[9] - mx);
    float e2 = __expf(o12[10] - mx), e3 = __expf(o12[11] - mx);
    float inv = fast_rcp(e0 + e1 + e2 + e3);
    float wk4[4] = {e0 * inv, e1 * inv, e2 * inv, e3 * inv};
    float xc = (px + 0.5f) * ((float)WC / (float)W) - 0.5f;
    float yc = (py + 0.5f) * ((float)HC / (float)H) - 0.5f;
#pragma unroll
    for (int k = 0; k < 4; ++k) {
        float ix = fminf(fmaxf(xc + 2.0f * tanh_f(o12[2 * k]),     0.0f), (float)(WC - 1));
        float iy = fminf(fmaxf(yc + 2.0f * tanh_f(o12[2 * k + 1]), 0.0f), (float)(HC - 1));
        float x0f = floorf(ix), y0f = floorf(iy);
        int x0 = (int)x0f, y0 = (int)y0f;
        int x1 = min(x0 + 1, WC - 1), y1 = min(y0 + 1, HC - 1);
        float wx = ix - x0f, wy = iy - y0f;
        float wk = wk4[k];
        zoff[4 * k + 0] = (y0 * WC + x0) * C; wgt[4 * k + 0] = (1.0f - wx) * (1.0f - wy) * wk;
        zoff[4 * k + 1] = (y0 * WC + x1) * C; wgt[4 * k + 1] = wx * (1.0f - wy) * wk;
        zoff[4 * k + 2] = (y1 * WC + x0) * C; wgt[4 * k + 2] = (1.0f - wx) * wy * wk;
        zoff[4 * k + 3] = (y1 * WC + x1) * C; wgt[4 * k + 3] = wx * wy * wk;
    }
}

// ---- one head per block (blockIdx.z): MFMA 3x3 conv + gather tail + means -
// LDS union: q tile (20736 B) is dead after the MFMA loop; hidw (9216 B)
// and ysum (512 B) reuse it -> 20.7 KB/block.
// launch_bounds (256,4): 128-VGPR budget. (256,6) forced 40 VGPR -> scratch
// spill of vv[16]/off/wg (+88MB FETCH, +88MB WRITE). Do NOT lower this.
__global__ __launch_bounds__(256, 4) void head_deform_kernel(
        const ushort_t* __restrict__ qpad,
        const ushort_t* __restrict__ z1, const ushort_t* __restrict__ z2,
        const ushort_t* __restrict__ w1ra, const ushort_t* __restrict__ w1rb,
        const float* __restrict__ w2a, const float* __restrict__ b2a,
        const float* __restrict__ w2b, const float* __restrict__ b2b,
        float* __restrict__ y1, float* __restrict__ y2, float* __restrict__ dall) {
    __shared__ __align__(16) char smem[TAREA * C * 2];      // 20736 B
    ushort_t* tile = (ushort_t*)smem;
    unsigned* hidw = (unsigned*)smem;                       // bytes [0, 9216)
    float (*ysum)[32] = (float (*)[32])(smem + 9216);       // bytes [9216, 9728)
    int tid = threadIdx.x, b = blockIdx.y, hsel = blockIdx.z;
    int ox = (blockIdx.x & 15) * TILE, oy = (blockIdx.x >> 4) * TILE;
    int lane = tid & 63, wv = tid >> 6;
    int n15 = lane & 15, quad = lane >> 4;
    int tx = tid & 15, ty = tid >> 4;

    // stage q tile (rows contiguous in padded channel-last q)
    {
        const ushort_t* base = qpad + ((size_t)b * WP + oy) * WP * 32;
        uint4* tl = (uint4*)tile;
        for (int i = tid; i < 1296; i += 256) {      // 18 rows * 72 16B-chunks
            int yy = i / 72, r = i - yy * 72;
            tl[i] = *(const uint4*)(base + ((size_t)yy * WP + ox) * 32 + r * 8);
        }
    }
    __syncthreads();

    const ushort_t* w1r = hsel ? w1rb : w1ra;
    bf16x8 af[9];
#pragma unroll
    for (int j = 0; j < 9; ++j)
        af[j] = *(const bf16x8*)(w1r + n15 * 288 + j * 32 + quad * 8);
    unsigned pk[8];
#pragma unroll
    for (int g = 0; g < 4; ++g) {
        int yrow = wv * 4 + g;
        f32x4 acc = {0.0f, 0.0f, 0.0f, 0.0f};
#pragma unroll
        for (int jy = 0; jy < 3; ++jy)
#pragma unroll
            for (int jx = 0; jx < 3; ++jx) {
                const bf16x8* bp = (const bf16x8*)(tile +
                    ((yrow + jy) * HALO + n15 + jx) * 32 + quad * 8);
                acc = __builtin_amdgcn_mfma_f32_16x16x32_bf16(
                    af[jy * 3 + jx], *bp, acc, 0, 0, 0);
            }
        pk[2 * g]     = (unsigned)f2b(acc[0]) | ((unsigned)f2b(acc[1]) << 16);
        pk[2 * g + 1] = (unsigned)f2b(acc[2]) | ((unsigned)f2b(acc[3]) << 16);
    }
    __syncthreads();   // ALL waves done reading tile before hidw overwrites it
#pragma unroll
    for (int g = 0; g < 4; ++g) {
        int pxl = (wv * 4 + g) * 16 + n15;
        hidw[pxl * 9 + quad * 2]     = pk[2 * g];
        hidw[pxl * 9 + quad * 2 + 1] = pk[2 * g + 1];
    }
    // hidw write->read is same-wave (pxl in [wv*64, wv*64+64)); lgkmcnt covers it
    float hid[CH];
#pragma unroll
    for (int j = 0; j < 8; ++j) {
        unsigned u = hidw[tid * 9 + j];
        hid[2 * j]     = silu_f(bl(u));
        hid[2 * j + 1] = silu_f(bh(u));
    }

    // ---- tail for this head ----
    const float* w2 = hsel ? w2b : w2a;
    const float* bs = hsel ? b2b : b2a;
    float o12[CO];
#pragma unroll
    for (int j = 0; j < CO; ++j) {
        float a = bs[j];
#pragma unroll
        for (int i = 0; i < CH; ++i) a += w2[j * CH + i] * hid[i];
        o12[j] = a;
    }
    int px = ox + tx, py = oy + ty;
    int off[16]; float wg[16];
    if (hsel == 0) calc_off<H1, W1>(o12, px, py, off, wg);
    else           calc_off<H2, W2>(o12, px, py, off, wg);

    const ushort_t* zb = hsel ? z2 + (size_t)b * HW2 * C : z1 + (size_t)b * HW1 * C;
    int p = py * W + px;
    float* d = (hsel ? y2 : y1) + (size_t)b * C * HW + p;

#pragma unroll
    for (int c8 = 0; c8 < 4; ++c8) {
        uint4 vv[16];
#pragma unroll
        for (int j = 0; j < 16; ++j)
            vv[j] = *(const uint4*)(zb + off[j] + c8 * 8);
        f32x4 lo = {0.0f, 0.0f, 0.0f, 0.0f};
        f32x4 hi = {0.0f, 0.0f, 0.0f, 0.0f};
#pragma unroll
        for (int j = 0; j < 16; ++j) {
            float wj = wg[j];
            lo[0] += wj * bl(vv[j].x); lo[1] += wj * bh(vv[j].x);
            lo[2] += wj * bl(vv[j].y); lo[3] += wj * bh(vv[j].y);
            hi[0] += wj * bl(vv[j].z); hi[1] += wj * bh(vv[j].z);
            hi[2] += wj * bl(vv[j].w); hi[3] += wj * bh(vv[j].w);
        }
#pragma unroll
        for (int k = 0; k < 4; ++k) {
            d[(size_t)(c8 * 8 + k) * HW]     = lo[k];
            d[(size_t)(c8 * 8 + 4 + k) * HW] = hi[k];
        }
        // channel means: butterfly-split reduce (10 shuffles for 8 channels)
        float s = red8_ch(lo[0], lo[1], lo[2], lo[3], hi[0], hi[1], hi[2], hi[3], lane);
        if (lane < 8)
            ysum[wv][c8 * 8 + ((lane & 1) * 4 + (lane & 2) + ((lane >> 2) & 1))] = s;
    }
    __syncthreads();
    if (tid < 32) {
        float s = ysum[0][tid] + ysum[1][tid] + ysum[2][tid] + ysum[3][tid];
        atomicAdd(&dall[b * 96 + 32 + hsel * 32 + tid], s * (1.0f / HW));
    }
}

// ---- gating MLP + softmax -> alpha[B*3] -----------------------------------
__global__ void gate_kernel(const float* __restrict__ dall,
                            const float* __restrict__ w1, const float* __restrict__ b1,
                            const float* __restrict__ w2, const float* __restrict__ b2,
                            float* __restrict__ alpha) {
    __shared__ float hid[B][32];
    int tid = threadIdx.x;
    int b = tid >> 5, j = tid & 31;
    float a = b1[j];
    for (int k = 0; k < 96; ++k) a += dall[b * 96 + k] * w1[k * 32 + j];
    hid[b][j] = silu_f(a);
    __syncthreads();
    if (j == 0) {
        float lg[3];
#pragma unroll
        for (int t = 0; t < 3; ++t) {
            float acc = b2[t];
            for (int jj = 0; jj < 32; ++jj) acc += hid[b][jj] * w2[jj * 3 + t];
            lg[t] = acc;
        }
        float mx = fmaxf(lg[0], fmaxf(lg[1], lg[2]));
        float e0 = __expf(lg[0] - mx), e1 = __expf(lg[1] - mx), e2 = __expf(lg[2] - mx);
        float inv = fast_rcp(e0 + e1 + e2);
        alpha[b * 3 + 0] = e0 * inv;
        alpha[b * 3 + 1] = e1 * inv;
        alpha[b * 3 + 2] = e2 * inv;
    }
}

// ---- fused mix + final 1x1 conv + residual (2 pixels/thread, packed) ------
__global__ __launch_bounds__(256, 4) void final_kernel(
        const float* __restrict__ x,
        const float* __restrict__ z0, const float* __restrict__ y1,
        const float* __restrict__ y2, const float* __restrict__ alpha,
        const float* __restrict__ fw, float* __restrict__ out) {
    __shared__ float ws[C * C];
    for (int i = threadIdx.x; i < C * C; i += blockDim.x) ws[i] = fw[i];
    __syncthreads();
    int idx = blockIdx.x * blockDim.x + threadIdx.x;
    constexpr int HP = HW / 2;
    if (idx >= B * HP) return;
    int b = idx / HP, p = (idx - b * HP) * 2;
    float a0 = alpha[b * 3], a1 = alpha[b * 3 + 1], a2 = alpha[b * 3 + 2];
    size_t base = (size_t)b * C * HW + p;
    v2f mix[C];
#pragma unroll
    for (int i = 0; i < C; ++i) {
        size_t e = base + (size_t)i * HW;
        v2f za = *(const v2f*)(z0 + e);
        v2f ya = *(const v2f*)(y1 + e);
        v2f yb = *(const v2f*)(y2 + e);
        mix[i] = a0 * za + a1 * ya + a2 * yb;
    }
#pragma unroll 4
    for (int o = 0; o < C; ++o) {
        v2f acc = {0.0f, 0.0f};
#pragma unroll
        for (int i = 0; i < C; ++i) acc += ws[o * C + i] * mix[i];
        size_t e = base + (size_t)o * HW;
        v2f xr = *(const v2f*)(x + e);
        *(v2f*)(out + e) = acc + xr;
    }
}

// ---------------------------------------------------------------------------
extern "C" void kernel_launch(void* const* d_in, const int* in_sizes, int n_in,
                              void* d_out, int out_size, void* d_ws, size_t ws_size,
                              hipStream_t stream) {
    const float* x       = (const float*)d_in[0];
    const float* ds_dw[3] = {(const float*)d_in[1],  (const float*)d_in[7],  (const float*)d_in[13]};
    const float* ds_pw[3] = {(const float*)d_in[2],  (const float*)d_in[8],  (const float*)d_in[14]};
    const float* ds_g[3]  = {(const float*)d_in[3],  (const float*)d_in[9],  (const float*)d_in[15]};
    const float* ds_b[3]  = {(const float*)d_in[4],  (const float*)d_in[10], (const float*)d_in[16]};
    const float* ds_m[3]  = {(const float*)d_in[5],  (const float*)d_in[11], (const float*)d_in[17]};
    const float* ds_v[3]  = {(const float*)d_in[6],  (const float*)d_in[12], (const float*)d_in[18]};
    const float* qproj_w = (const float*)d_in[19];
    const float* h1_w1   = (const float*)d_in[20];
    const float* h1_w2   = (const float*)d_in[21];
    const float* h1_b2   = (const float*)d_in[22];
    const float* h2_w1   = (const float*)d_in[23];
    const float* h2_w2   = (const float*)d_in[24];
    const float* h2_b2   = (const float*)d_in[25];
    const float* r_w1    = (const float*)d_in[26];
    const float* r_b1    = (const float*)d_in[27];
    const float* r_w2    = (const float*)d_in[28];
    const float* r_b2    = (const float*)d_in[29];
    const float* final_w = (const float*)d_in[30];
    float* out = (float*)d_out;

    constexpr size_t N0 = (size_t)B * C * HW;
    constexpr size_t N1 = (size_t)B * C * HW1;
    constexpr size_t N2 = (size_t)B * C * HW2;
    constexpr size_t NQ = ((size_t)B * WP * WP * 32 + 1) / 2;   // qpad (u16) in floats

    float* w = (float*)d_ws;
    float* z0   = w; w += N0;      // plane fp32
    float* y1   = w; w += N0;      // plane fp32
    float* y2   = w; w += N0;      // plane fp32
    ushort_t* z1cl = (ushort_t*)w; w += N1 / 2;   // bf16 channel-last
    ushort_t* z2cl = (ushort_t*)w; w += N2 / 2;   // bf16 channel-last
    float* s1   = w; w += N1;
    float* s2   = w; w += N2;
    ushort_t* qpad = (ushort_t*)w; w += NQ;
    ushort_t* w1ra = (ushort_t*)w; w += 2304;   // 4608 bf16
    ushort_t* w1rb = (ushort_t*)w; w += 2304;
    float* dall  = w; w += 512;
    float* alpha = w; w += 16;
    (void)ws_size; (void)in_sizes; (void)n_in; (void)out_size;

    const int T = 256;
    auto g = [](size_t n, int t) { return (int)((n + t - 1) / t); };

    pre_kernel<<<g(N1 + 4112 + 512 + 9216, T), T, 0, stream>>>(
        x, s1, qpad, dall, h1_w1, h2_w1, w1ra, w1rb);
    pool4_kernel<<<g(N2, T), T, 0, stream>>>(s1, s2);

    fused_ds_kernel<false><<<dim3((H / TILE) * (W / TILE), B), T, 0, stream>>>(
        x, ds_dw[0], ds_pw[0], ds_g[0], ds_b[0], ds_m[0], ds_v[0], qproj_w,
        z0, nullptr, qpad, dall, H, W, W / TILE);
    fused_ds_kernel<true><<<dim3((H1 / TILE) * (W1 / TILE), B), T, 0, stream>>>(
        s1, ds_dw[1], ds_pw[1], ds_g[1], ds_b[1], ds_m[1], ds_v[1], nullptr,
        nullptr, z1cl, nullptr, nullptr, H1, W1, W1 / TILE);
    fused_ds_kernel<true><<<dim3((H2 / TILE) * (W2 / TILE), B), T, 0, stream>>>(
        s2, ds_dw[2], ds_pw[2], ds_g[2], ds_b[2], ds_m[2], ds_v[2], nullptr,
        nullptr, z2cl, nullptr, nullptr, H2, W2, W2 / TILE);

    head_deform_kernel<<<dim3((H / TILE) * (W / TILE), B, 2), T, 0, stream>>>(
        qpad, z1cl, z2cl, w1ra, w1rb, h1_w2, h1_b2, h2_w2, h2_b2, y1, y2, dall);

    gate_kernel<<<1, 128, 0, stream>>>(dall, r_w1, r_b1, r_w2, r_b2, alpha);

    final_kernel<<<g((size_t)B * HW / 2, T), T, 0, stream>>>(x, z0, y1, y2, alpha, final_w, out);
}

// Round 3
// 299.155 us; speedup vs baseline: 1.3252x; 1.0942x over previous
//
#include <hip/hip_runtime.h>
#include <math.h>

// ---------------------------------------------------------------------------
// CSDM pipeline on MI355X. fp32 in/out, fp32/bf16 intermediates in d_ws.
// B=4, C=32, H=W=256. MFMA head conv; bf16 channel-last gather sources
// (16B load = 8 channels); batched gather loads (16 in flight); channel
// means fused into producer kernels (no mean pass).
// Layout law (r6): bulk WRITES plane-major dense; gather READS channel-last.
// r7: head kernel split per-head across blockIdx.z (2048 blocks), LDS
// union (tile reused for hidw/ysum -> 20.7KB), butterfly-split mean reduce.
// r8: launch_bounds 6->4. (256,6) forced VGPR=40 -> scratch spill of the
// 16-deep gather batch (+88MB FETCH & +88MB WRITE, matched = spill
// signature). 128-VGPR budget holds vv[16]+off+wg+af with zero spills.
// r9: z1/z2 ds dispatches ran at 1 / 0.25 blocks-per-CU on an empty machine;
// merged all three ds levels into ONE 1344-block launch (level by blockIdx
// range). pool4 folded into pre (s2 = 4x4 mean of x, same as reference).
// z0 channel-means switched to butterfly red8_ch. 8 dispatches -> 5.
// ---------------------------------------------------------------------------

constexpr int B = 4, C = 32, H = 256, W = 256;
constexpr int HW = H * W;
constexpr int H1 = 128, W1 = 128, HW1 = H1 * W1;
constexpr int H2 = 64,  W2 = 64,  HW2 = H2 * W2;
constexpr int CH = 16;   // head hidden channels
constexpr int CO = 12;   // head output channels
constexpr int TILE = 16;
constexpr int HALO = 18;
constexpr int TAREA = HALO * HALO;   // 324
constexpr int WP = 258;              // padded q edge

typedef unsigned short ushort_t;
typedef __attribute__((ext_vector_type(8))) short bf16x8;
typedef __attribute__((ext_vector_type(4))) float f32x4;
typedef __attribute__((ext_vector_type(2))) float v2f;

static __device__ __forceinline__ float fast_rcp(float x) { return __builtin_amdgcn_rcpf(x); }
static __device__ __forceinline__ float silu_f(float x) { return x * fast_rcp(1.0f + __expf(-x)); }
static __device__ __forceinline__ v2f silu2(v2f x) {
    v2f r; r.x = silu_f(x.x); r.y = silu_f(x.y); return r;
}
static __device__ __forceinline__ float tanh_f(float x) {
    float xc = fminf(fmaxf(x, -15.0f), 15.0f);
    float e = __expf(2.0f * xc);
    return (e - 1.0f) * fast_rcp(e + 1.0f);
}
static __device__ __forceinline__ ushort_t f2b(float f) {   // fp32 -> bf16 RNE
    unsigned u = __float_as_uint(f);
    return (ushort_t)((u + 0x7fffu + ((u >> 16) & 1u)) >> 16);
}
static __device__ __forceinline__ float bl(unsigned u) { return __uint_as_float(u << 16); }
static __device__ __forceinline__ float bh(unsigned u) { return __uint_as_float(u & 0xffff0000u); }

// Multi-value butterfly: 8 per-thread channel values -> full-wave sum of
// channel c(lane)=4*b0+2*b1+b2 in lane. 10 shuffles vs 48 for 8 wave_sums.
static __device__ __forceinline__ float red8_ch(float v0, float v1, float v2, float v3,
                                                float v4, float v5, float v6, float v7,
                                                int lane) {
    bool q0 = (lane & 1) != 0, q1 = (lane & 2) != 0, q2 = (lane & 4) != 0;
    float a0 = (q0 ? v4 : v0) + __shfl_xor(q0 ? v0 : v4, 1, 64);
    float a1 = (q0 ? v5 : v1) + __shfl_xor(q0 ? v1 : v5, 1, 64);
    float a2 = (q0 ? v6 : v2) + __shfl_xor(q0 ? v2 : v6, 1, 64);
    float a3 = (q0 ? v7 : v3) + __shfl_xor(q0 ? v3 : v7, 1, 64);
    float c0 = (q1 ? a2 : a0) + __shfl_xor(q1 ? a0 : a2, 2, 64);
    float c1 = (q1 ? a3 : a1) + __shfl_xor(q1 ? a1 : a3, 2, 64);
    float e  = (q2 ? c1 : c0) + __shfl_xor(q2 ? c0 : c1, 4, 64);
    e += __shfl_xor(e, 8, 64);
    e += __shfl_xor(e, 16, 64);
    e += __shfl_xor(e, 32, 64);
    return e;
}

// ---- pre: pool2 + pool4 + qpad border + dall zero + w1 bf16 reorder -------
__global__ void pre_kernel(const float* __restrict__ x, float* __restrict__ s1,
                           float* __restrict__ s2,
                           ushort_t* __restrict__ qpad, float* __restrict__ dall,
                           const float* __restrict__ h1w1, const float* __restrict__ h2w1,
                           ushort_t* __restrict__ w1ra, ushort_t* __restrict__ w1rb) {
    int idx = blockIdx.x * blockDim.x + threadIdx.x;
    constexpr int NP = B * C * HW1;
    constexpr int NP2 = B * C * HW2;
    if (idx < NP) {
        int wo = idx % W1; int t = idx / W1;
        int ho = t % H1;   t /= H1;
        const float* src = x + ((size_t)t * H + (size_t)ho * 2) * W + (size_t)wo * 2;
        s1[idx] = (src[0] + src[1] + src[W] + src[W + 1]) * 0.25f;
        return;
    }
    int i = idx - NP;
    if (i < NP2) {                        // s2 = 4x4 mean of x (== avgpool(x,4))
        int wo = i % W2; int t = i / W2;
        int ho = t % H2;   t /= H2;
        const float* src = x + ((size_t)t * H + (size_t)ho * 4) * W + (size_t)wo * 4;
        float s = 0.0f;
#pragma unroll
        for (int r = 0; r < 4; ++r) {
            const float* rp = src + (size_t)r * W;
            s += (rp[0] + rp[1]) + (rp[2] + rp[3]);
        }
        s2[i] = s * 0.0625f;
        return;
    }
    i -= NP2;
    if (i < 4112) {                       // qpad border (4*1028)
        int b = i / 1028, r = i % 1028;
        int y, xx;
        if (r < 258)      { y = 0;           xx = r; }
        else if (r < 516) { y = 257;         xx = r - 258; }
        else if (r < 772) { y = r - 516 + 1; xx = 0; }
        else              { y = r - 772 + 1; xx = 257; }
        uint4 z4 = {0, 0, 0, 0};
        uint4* p = (uint4*)(qpad + (((size_t)b * WP + y) * WP + xx) * 32);
        p[0] = z4; p[1] = z4; p[2] = z4; p[3] = z4;
        return;
    }
    i -= 4112;
    if (i < 512) { dall[i] = 0.0f; return; }
    i -= 512;
    if (i < 4608) {                       // w1ra[o*288 + tap*32 + ci]
        int o = i / 288, k = i - o * 288;
        int j = k >> 5, ci = k & 31;
        w1ra[i] = f2b(h1w1[(o * C + ci) * 9 + j]);
        return;
    }
    i -= 4608;
    if (i < 4608) {
        int o = i / 288, k = i - o * 288;
        int j = k >> 5, ci = k & 31;
        w1rb[i] = f2b(h2w1[(o * C + ci) * 9 + j]);
    }
}

// ---- fused ds_block, all 3 levels in one launch ---------------------------
// blockIdx.x: [0,1024) level0 (z0+qproj+means), [1024,1280) level1 (z1cl),
// [1280,1344) level2 (z2cl). Level>0: bf16 channel-last gather source.
struct DsParams {
    const float* in; const float* dw; const float* pw;
    const float* g;  const float* b;  const float* m; const float* v;
};

__global__ __launch_bounds__(256, 4) void fused_ds_all_kernel(
        DsParams P0, DsParams P1, DsParams P2, const float* __restrict__ qw,
        float* __restrict__ z0out, ushort_t* __restrict__ z1cl,
        ushort_t* __restrict__ z2cl, ushort_t* __restrict__ qout,
        float* __restrict__ dall) {
    __shared__ unsigned tileu[16 * TAREA];     // 2-ch interleaved bf16, 20736 B
    __shared__ v2f dwp[16 * 9];
    __shared__ v2f pwp[C * 16];                // pwp[ci*16+o2] = {w[2o2][ci], w[2o2+1][ci]}
    __shared__ v2f qwp[C * 16];
    __shared__ v2f scale2[16], shift2[16];
    __shared__ float zsum[4][32];

    int bx = blockIdx.x;
    int level = (bx < 1024) ? 0 : (bx < 1280 ? 1 : 2);
    int rel = bx - ((level == 0) ? 0 : (level == 1 ? 1024 : 1280));
    int Hs = (level == 0) ? H : (level == 1 ? H1 : H2);
    int Ws = Hs;
    int tilesX = Ws / TILE;
    int tilesT = tilesX * (Hs / TILE);
    int b = rel / tilesT;
    int tile = rel - b * tilesT;
    int ox = (tile % tilesX) * TILE;
    int oy = (tile / tilesX) * TILE;
    DsParams P = (level == 0) ? P0 : (level == 1 ? P1 : P2);
    int HWs = Hs * Ws;
    int tid = threadIdx.x;

    for (int i = tid; i < 16 * 9; i += 256) {
        int c2 = i / 9, j = i - c2 * 9;
        dwp[i] = (v2f){P.dw[(2 * c2) * 9 + j], P.dw[(2 * c2 + 1) * 9 + j]};
    }
    for (int i = tid; i < C * 16; i += 256) {
        int ci = i >> 4, o2 = i & 15;
        pwp[i] = (v2f){P.pw[(2 * o2) * C + ci], P.pw[(2 * o2 + 1) * C + ci]};
        if (level == 0) qwp[i] = (v2f){qw[(2 * o2) * C + ci], qw[(2 * o2 + 1) * C + ci]};
    }
    if (tid < 16) {
        float s0 = P.g[2 * tid] * rsqrtf(P.v[2 * tid] + 1e-5f);
        float s1v = P.g[2 * tid + 1] * rsqrtf(P.v[2 * tid + 1] + 1e-5f);
        scale2[tid] = (v2f){s0, s1v};
        shift2[tid] = (v2f){P.b[2 * tid] - P.m[2 * tid] * s0,
                            P.b[2 * tid + 1] - P.m[2 * tid + 1] * s1v};
    }
    const float* src = P.in + (size_t)b * C * HWs;
    for (int i = tid; i < 16 * TAREA; i += 256) {
        int c2 = i / TAREA, r = i - c2 * TAREA;
        int yy = r / HALO, xx = r - yy * HALO;
        int gy = oy - 1 + yy, gx = ox - 1 + xx;
        float v0 = 0.0f, v1 = 0.0f;
        if (gy >= 0 && gy < Hs && gx >= 0 && gx < Ws) {
            const float* sp = src + (size_t)(2 * c2) * HWs + gy * Ws + gx;
            v0 = sp[0]; v1 = sp[HWs];
        }
        tileu[i] = (unsigned)f2b(v0) | ((unsigned)f2b(v1) << 16);
    }
    __syncthreads();

    int tx = tid & 15, ty = tid >> 4;
    int off[9];
#pragma unroll
    for (int jy = 0; jy < 3; ++jy)
#pragma unroll
        for (int jx = 0; jx < 3; ++jx)
            off[jy * 3 + jx] = (ty + jy) * HALO + tx + jx;

    v2f t2[16];
#pragma unroll
    for (int c2 = 0; c2 < 16; ++c2) {
        v2f s = {0.0f, 0.0f};
        const unsigned* tp = tileu + c2 * TAREA;
#pragma unroll
        for (int j = 0; j < 9; ++j) {
            unsigned u = tp[off[j]];
            v2f val = {bl(u), bh(u)};
            s += dwp[c2 * 9 + j] * val;
        }
        t2[c2] = s;
    }

    v2f acc2[16];
#pragma unroll
    for (int o2 = 0; o2 < 16; ++o2) acc2[o2] = (v2f){0.0f, 0.0f};
#pragma unroll
    for (int i2 = 0; i2 < 16; ++i2) {
        float ta = t2[i2].x, tb = t2[i2].y;
        const v2f* r0 = pwp + (2 * i2) * 16;
        const v2f* r1 = r0 + 16;
#pragma unroll
        for (int o2 = 0; o2 < 16; ++o2)
            acc2[o2] += r0[o2] * ta + r1[o2] * tb;
    }
#pragma unroll
    for (int o2 = 0; o2 < 16; ++o2)
        acc2[o2] = silu2(acc2[o2] * scale2[o2] + shift2[o2]);

    int px = ox + tx, py = oy + ty;
    int p = py * Ws + px;
    if (level > 0) {
        // bf16 channel-last: 32 ch -> 16 uints -> 4 uint4 stores (64 B/px)
        ushort_t* outcl = (level == 1) ? z1cl : z2cl;
        unsigned up[16];
#pragma unroll
        for (int j = 0; j < 16; ++j)
            up[j] = (unsigned)f2b(acc2[j].x) | ((unsigned)f2b(acc2[j].y) << 16);
        uint4* dst = (uint4*)(outcl + ((size_t)b * HWs + p) * C);
#pragma unroll
        for (int j = 0; j < 4; ++j)
            dst[j] = make_uint4(up[4 * j], up[4 * j + 1], up[4 * j + 2], up[4 * j + 3]);
    } else {
        float* dst = z0out + (size_t)b * C * HWs + p;
#pragma unroll
        for (int o2 = 0; o2 < 16; ++o2) {
            dst[(size_t)(2 * o2) * HWs] = acc2[o2].x;
            dst[(size_t)(2 * o2 + 1) * HWs] = acc2[o2].y;
        }
        // q projection -> bf16 padded channel-last
        v2f q2[16];
#pragma unroll
        for (int o2 = 0; o2 < 16; ++o2) q2[o2] = (v2f){0.0f, 0.0f};
#pragma unroll
        for (int i2 = 0; i2 < 16; ++i2) {
            float ta = acc2[i2].x, tb = acc2[i2].y;
            const v2f* r0 = qwp + (2 * i2) * 16;
            const v2f* r1 = r0 + 16;
#pragma unroll
            for (int o2 = 0; o2 < 16; ++o2)
                q2[o2] += r0[o2] * ta + r1[o2] * tb;
        }
        unsigned up[16];
#pragma unroll
        for (int j = 0; j < 16; ++j)
            up[j] = (unsigned)f2b(q2[j].x) | ((unsigned)f2b(q2[j].y) << 16);
        uint4* qd = (uint4*)(qout + (((size_t)b * WP + py + 1) * WP + px + 1) * 32);
#pragma unroll
        for (int j = 0; j < 4; ++j)
            qd[j] = make_uint4(up[4 * j], up[4 * j + 1], up[4 * j + 2], up[4 * j + 3]);
        // z0 channel means: butterfly red8_ch (40 shuffles vs 192 wave_sum)
        int lane = tid & 63, wv = tid >> 6;
#pragma unroll
        for (int gq = 0; gq < 4; ++gq) {
            float s = red8_ch(acc2[4 * gq].x,     acc2[4 * gq].y,
                              acc2[4 * gq + 1].x, acc2[4 * gq + 1].y,
                              acc2[4 * gq + 2].x, acc2[4 * gq + 2].y,
                              acc2[4 * gq + 3].x, acc2[4 * gq + 3].y, lane);
            if (lane < 8)
                zsum[wv][8 * gq + ((lane & 1) * 4 + (lane & 2) + ((lane >> 2) & 1))] = s;
        }
        __syncthreads();
        if (tid < 32)
            atomicAdd(&dall[b * 96 + tid],
                      (zsum[0][tid] + zsum[1][tid] + zsum[2][tid] + zsum[3][tid]) * (1.0f / HW));
    }
}

// ---- offsets/weights for one head (halfword offsets into bf16 z) ----------
template<int HC, int WC>
static __device__ __forceinline__ void calc_off(const float* o12, int px, int py,
                                                int* zoff, float* wgt) {
    float mx = fmaxf(fmaxf(o12[8], o12[9]), fmaxf(o12[10], o12[11]));
    float e0 = __expf(o12[8] - mx), e1 = __expf(o12[9] - mx);
    float e2 = __expf(o12[10] - mx), e3 = __expf(o12[11] - mx);
    float inv = fast_rcp(e0 + e1 + e2 + e3);
    float wk4[4] = {e0 * inv, e1 * inv, e2 * inv, e3 * inv};
    float xc = (px + 0.5f) * ((float)WC / (float)W) - 0.5f;
    float yc = (py + 0.5f) * ((float)HC / (float)H) - 0.5f;
#pragma unroll
    for (int k = 0; k < 4; ++k) {
        float ix = fminf(fmaxf(xc + 2.0f * tanh_f(o12[2 * k]),     0.0f), (float)(WC - 1));
        float iy = fminf(fmaxf(yc + 2.0f * tanh_f(o12[2 * k + 1]), 0.0f), (float)(HC - 1));
        float x0f = floorf(ix), y0f = floorf(iy);
        int x0 = (int)x0f, y0 = (int)y0f;
        int x1 = min(x0 + 1, WC - 1), y1 = min(y0 + 1, HC - 1);
        float wx = ix - x0f, wy = iy - y0f;
        float wk = wk4[k];
        zoff[4 * k + 0] = (y0 * WC + x0) * C; wgt[4 * k + 0] = (1.0f - wx) * (1.0f - wy) * wk;
        zoff[4 * k + 1] = (y0 * WC + x1) * C; wgt[4 * k + 1] = wx * (1.0f - wy) * wk;
        zoff[4 * k + 2] = (y1 * WC + x0) * C; wgt[4 * k + 2] = (1.0f - wx) * wy * wk;
        zoff[4 * k + 3] = (y1 * WC + x1) * C; wgt[4 * k + 3] = wx * wy * wk;
    }
}

// ---- one head per block (blockIdx.z): MFMA 3x3 conv + gather tail + means -
// LDS union: q tile (20736 B) is dead after the MFMA loop; hidw (9216 B)
// and ysum (512 B) reuse it -> 20.7 KB/block.
// launch_bounds (256,4): 128-VGPR budget. (256,6) forced 40 VGPR -> scratch
// spill of vv[16]/off/wg (+88MB FETCH, +88MB WRITE). Do NOT lower this.
__global__ __launch_bounds__(256, 4) void head_deform_kernel(
        const ushort_t* __restrict__ qpad,
        const ushort_t* __restrict__ z1, const ushort_t* __restrict__ z2,
        const ushort_t* __restrict__ w1ra, const ushort_t* __restrict__ w1rb,
        const float* __restrict__ w2a, const float* __restrict__ b2a,
        const float* __restrict__ w2b, const float* __restrict__ b2b,
        float* __restrict__ y1, float* __restrict__ y2, float* __restrict__ dall) {
    __shared__ __align__(16) char smem[TAREA * C * 2];      // 20736 B
    ushort_t* tile = (ushort_t*)smem;
    unsigned* hidw = (unsigned*)smem;                       // bytes [0, 9216)
    float (*ysum)[32] = (float (*)[32])(smem + 9216);       // bytes [9216, 9728)
    int tid = threadIdx.x, b = blockIdx.y, hsel = blockIdx.z;
    int ox = (blockIdx.x & 15) * TILE, oy = (blockIdx.x >> 4) * TILE;
    int lane = tid & 63, wv = tid >> 6;
    int n15 = lane & 15, quad = lane >> 4;
    int tx = tid & 15, ty = tid >> 4;

    // stage q tile (rows contiguous in padded channel-last q)
    {
        const ushort_t* base = qpad + ((size_t)b * WP + oy) * WP * 32;
        uint4* tl = (uint4*)tile;
        for (int i = tid; i < 1296; i += 256) {      // 18 rows * 72 16B-chunks
            int yy = i / 72, r = i - yy * 72;
            tl[i] = *(const uint4*)(base + ((size_t)yy * WP + ox) * 32 + r * 8);
        }
    }
    __syncthreads();

    const ushort_t* w1r = hsel ? w1rb : w1ra;
    bf16x8 af[9];
#pragma unroll
    for (int j = 0; j < 9; ++j)
        af[j] = *(const bf16x8*)(w1r + n15 * 288 + j * 32 + quad * 8);
    unsigned pk[8];
#pragma unroll
    for (int g = 0; g < 4; ++g) {
        int yrow = wv * 4 + g;
        f32x4 acc = {0.0f, 0.0f, 0.0f, 0.0f};
#pragma unroll
        for (int jy = 0; jy < 3; ++jy)
#pragma unroll
            for (int jx = 0; jx < 3; ++jx) {
                const bf16x8* bp = (const bf16x8*)(tile +
                    ((yrow + jy) * HALO + n15 + jx) * 32 + quad * 8);
                acc = __builtin_amdgcn_mfma_f32_16x16x32_bf16(
                    af[jy * 3 + jx], *bp, acc, 0, 0, 0);
            }
        pk[2 * g]     = (unsigned)f2b(acc[0]) | ((unsigned)f2b(acc[1]) << 16);
        pk[2 * g + 1] = (unsigned)f2b(acc[2]) | ((unsigned)f2b(acc[3]) << 16);
    }
    __syncthreads();   // ALL waves done reading tile before hidw overwrites it
#pragma unroll
    for (int g = 0; g < 4; ++g) {
        int pxl = (wv * 4 + g) * 16 + n15;
        hidw[pxl * 9 + quad * 2]     = pk[2 * g];
        hidw[pxl * 9 + quad * 2 + 1] = pk[2 * g + 1];
    }
    // hidw write->read is same-wave (pxl in [wv*64, wv*64+64)); lgkmcnt covers it
    float hid[CH];
#pragma unroll
    for (int j = 0; j < 8; ++j) {
        unsigned u = hidw[tid * 9 + j];
        hid[2 * j]     = silu_f(bl(u));
        hid[2 * j + 1] = silu_f(bh(u));
    }

    // ---- tail for this head ----
    const float* w2 = hsel ? w2b : w2a;
    const float* bs = hsel ? b2b : b2a;
    float o12[CO];
#pragma unroll
    for (int j = 0; j < CO; ++j) {
        float a = bs[j];
#pragma unroll
        for (int i = 0; i < CH; ++i) a += w2[j * CH + i] * hid[i];
        o12[j] = a;
    }
    int px = ox + tx, py = oy + ty;
    int off[16]; float wg[16];
    if (hsel == 0) calc_off<H1, W1>(o12, px, py, off, wg);
    else           calc_off<H2, W2>(o12, px, py, off, wg);

    const ushort_t* zb = hsel ? z2 + (size_t)b * HW2 * C : z1 + (size_t)b * HW1 * C;
    int p = py * W + px;
    float* d = (hsel ? y2 : y1) + (size_t)b * C * HW + p;

#pragma unroll
    for (int c8 = 0; c8 < 4; ++c8) {
        uint4 vv[16];
#pragma unroll
        for (int j = 0; j < 16; ++j)
            vv[j] = *(const uint4*)(zb + off[j] + c8 * 8);
        f32x4 lo = {0.0f, 0.0f, 0.0f, 0.0f};
        f32x4 hi = {0.0f, 0.0f, 0.0f, 0.0f};
#pragma unroll
        for (int j = 0; j < 16; ++j) {
            float wj = wg[j];
            lo[0] += wj * bl(vv[j].x); lo[1] += wj * bh(vv[j].x);
            lo[2] += wj * bl(vv[j].y); lo[3] += wj * bh(vv[j].y);
            hi[0] += wj * bl(vv[j].z); hi[1] += wj * bh(vv[j].z);
            hi[2] += wj * bl(vv[j].w); hi[3] += wj * bh(vv[j].w);
        }
#pragma unroll
        for (int k = 0; k < 4; ++k) {
            d[(size_t)(c8 * 8 + k) * HW]     = lo[k];
            d[(size_t)(c8 * 8 + 4 + k) * HW] = hi[k];
        }
        // channel means: butterfly-split reduce (10 shuffles for 8 channels)
        float s = red8_ch(lo[0], lo[1], lo[2], lo[3], hi[0], hi[1], hi[2], hi[3], lane);
        if (lane < 8)
            ysum[wv][c8 * 8 + ((lane & 1) * 4 + (lane & 2) + ((lane >> 2) & 1))] = s;
    }
    __syncthreads();
    if (tid < 32) {
        float s = ysum[0][tid] + ysum[1][tid] + ysum[2][tid] + ysum[3][tid];
        atomicAdd(&dall[b * 96 + 32 + hsel * 32 + tid], s * (1.0f / HW));
    }
}

// ---- gating MLP + softmax -> alpha[B*3] -----------------------------------
__global__ void gate_kernel(const float* __restrict__ dall,
                            const float* __restrict__ w1, const float* __restrict__ b1,
                            const float* __restrict__ w2, const float* __restrict__ b2,
                            float* __restrict__ alpha) {
    __shared__ float hid[B][32];
    int tid = threadIdx.x;
    int b = tid >> 5, j = tid & 31;
    float a = b1[j];
    for (int k = 0; k < 96; ++k) a += dall[b * 96 + k] * w1[k * 32 + j];
    hid[b][j] = silu_f(a);
    __syncthreads();
    if (j == 0) {
        float lg[3];
#pragma unroll
        for (int t = 0; t < 3; ++t) {
            float acc = b2[t];
            for (int jj = 0; jj < 32; ++jj) acc += hid[b][jj] * w2[jj * 3 + t];
            lg[t] = acc;
        }
        float mx = fmaxf(lg[0], fmaxf(lg[1], lg[2]));
        float e0 = __expf(lg[0] - mx), e1 = __expf(lg[1] - mx), e2 = __expf(lg[2] - mx);
        float inv = fast_rcp(e0 + e1 + e2);
        alpha[b * 3 + 0] = e0 * inv;
        alpha[b * 3 + 1] = e1 * inv;
        alpha[b * 3 + 2] = e2 * inv;
    }
}

// ---- fused mix + final 1x1 conv + residual (2 pixels/thread, packed) ------
__global__ __launch_bounds__(256, 4) void final_kernel(
        const float* __restrict__ x,
        const float* __restrict__ z0, const float* __restrict__ y1,
        const float* __restrict__ y2, const float* __restrict__ alpha,
        const float* __restrict__ fw, float* __restrict__ out) {
    __shared__ float ws[C * C];
    for (int i = threadIdx.x; i < C * C; i += blockDim.x) ws[i] = fw[i];
    __syncthreads();
    int idx = blockIdx.x * blockDim.x + threadIdx.x;
    constexpr int HP = HW / 2;
    if (idx >= B * HP) return;
    int b = idx / HP, p = (idx - b * HP) * 2;
    float a0 = alpha[b * 3], a1 = alpha[b * 3 + 1], a2 = alpha[b * 3 + 2];
    size_t base = (size_t)b * C * HW + p;
    v2f mix[C];
#pragma unroll
    for (int i = 0; i < C; ++i) {
        size_t e = base + (size_t)i * HW;
        v2f za = *(const v2f*)(z0 + e);
        v2f ya = *(const v2f*)(y1 + e);
        v2f yb = *(const v2f*)(y2 + e);
        mix[i] = a0 * za + a1 * ya + a2 * yb;
    }
#pragma unroll 4
    for (int o = 0; o < C; ++o) {
        v2f acc = {0.0f, 0.0f};
#pragma unroll
        for (int i = 0; i < C; ++i) acc += ws[o * C + i] * mix[i];
        size_t e = base + (size_t)o * HW;
        v2f xr = *(const v2f*)(x + e);
        *(v2f*)(out + e) = acc + xr;
    }
}

// ---------------------------------------------------------------------------
extern "C" void kernel_launch(void* const* d_in, const int* in_sizes, int n_in,
                              void* d_out, int out_size, void* d_ws, size_t ws_size,
                              hipStream_t stream) {
    const float* x       = (const float*)d_in[0];
    const float* ds_dw[3] = {(const float*)d_in[1],  (const float*)d_in[7],  (const float*)d_in[13]};
    const float* ds_pw[3] = {(const float*)d_in[2],  (const float*)d_in[8],  (const float*)d_in[14]};
    const float* ds_g[3]  = {(const float*)d_in[3],  (const float*)d_in[9],  (const float*)d_in[15]};
    const float* ds_b[3]  = {(const float*)d_in[4],  (const float*)d_in[10], (const float*)d_in[16]};
    const float* ds_m[3]  = {(const float*)d_in[5],  (const float*)d_in[11], (const float*)d_in[17]};
    const float* ds_v[3]  = {(const float*)d_in[6],  (const float*)d_in[12], (const float*)d_in[18]};
    const float* qproj_w = (const float*)d_in[19];
    const float* h1_w1   = (const float*)d_in[20];
    const float* h1_w2   = (const float*)d_in[21];
    const float* h1_b2   = (const float*)d_in[22];
    const float* h2_w1   = (const float*)d_in[23];
    const float* h2_w2   = (const float*)d_in[24];
    const float* h2_b2   = (const float*)d_in[25];
    const float* r_w1    = (const float*)d_in[26];
    const float* r_b1    = (const float*)d_in[27];
    const float* r_w2    = (const float*)d_in[28];
    const float* r_b2    = (const float*)d_in[29];
    const float* final_w = (const float*)d_in[30];
    float* out = (float*)d_out;

    constexpr size_t N0 = (size_t)B * C * HW;
    constexpr size_t N1 = (size_t)B * C * HW1;
    constexpr size_t N2 = (size_t)B * C * HW2;
    constexpr size_t NQ = ((size_t)B * WP * WP * 32 + 1) / 2;   // qpad (u16) in floats

    float* w = (float*)d_ws;
    float* z0   = w; w += N0;      // plane fp32
    float* y1   = w; w += N0;      // plane fp32
    float* y2   = w; w += N0;      // plane fp32
    ushort_t* z1cl = (ushort_t*)w; w += N1 / 2;   // bf16 channel-last
    ushort_t* z2cl = (ushort_t*)w; w += N2 / 2;   // bf16 channel-last
    float* s1   = w; w += N1;
    float* s2   = w; w += N2;
    ushort_t* qpad = (ushort_t*)w; w += NQ;
    ushort_t* w1ra = (ushort_t*)w; w += 2304;   // 4608 bf16
    ushort_t* w1rb = (ushort_t*)w; w += 2304;
    float* dall  = w; w += 512;
    float* alpha = w; w += 16;
    (void)ws_size; (void)in_sizes; (void)n_in; (void)out_size;

    const int T = 256;
    auto g = [](size_t n, int t) { return (int)((n + t - 1) / t); };

    pre_kernel<<<g(N1 + N2 + 4112 + 512 + 9216, T), T, 0, stream>>>(
        x, s1, s2, qpad, dall, h1_w1, h2_w1, w1ra, w1rb);

    DsParams p0 = {x,  ds_dw[0], ds_pw[0], ds_g[0], ds_b[0], ds_m[0], ds_v[0]};
    DsParams p1 = {s1, ds_dw[1], ds_pw[1], ds_g[1], ds_b[1], ds_m[1], ds_v[1]};
    DsParams p2 = {s2, ds_dw[2], ds_pw[2], ds_g[2], ds_b[2], ds_m[2], ds_v[2]};
    fused_ds_all_kernel<<<1344, T, 0, stream>>>(
        p0, p1, p2, qproj_w, z0, z1cl, z2cl, qpad, dall);

    head_deform_kernel<<<dim3((H / TILE) * (W / TILE), B, 2), T, 0, stream>>>(
        qpad, z1cl, z2cl, w1ra, w1rb, h1_w2, h1_b2, h2_w2, h2_b2, y1, y2, dall);

    gate_kernel<<<1, 128, 0, stream>>>(dall, r_w1, r_b1, r_w2, r_b2, alpha);

    final_kernel<<<g((size_t)B * HW / 2, T), T, 0, stream>>>(x, z0, y1, y2, alpha, final_w, out);
}

// Round 4
// 270.622 us; speedup vs baseline: 1.4649x; 1.1054x over previous
//
#include <hip/hip_runtime.h>
#include <math.h>

// ---------------------------------------------------------------------------
// CSDM pipeline on MI355X. fp32 in/out, fp32/bf16 intermediates in d_ws.
// B=4, C=32, H=W=256. MFMA head conv; bf16 channel-last gather sources
// (16B load = 8 channels); batched gather loads (16 in flight); channel
// means fused into producer kernels (no mean pass).
// Layout law (r6): bulk WRITES plane-major dense; gather READS channel-last.
// r7: head kernel split per-head across blockIdx.z (2048 blocks), LDS
// union (tile reused for hidw/ysum -> 20.7KB), butterfly-split mean reduce.
// r8: launch_bounds 6->4. (256,6) forced VGPR=40 -> scratch spill (+88MB
// FETCH & +88MB WRITE matched = spill signature). Do NOT lower bounds.
// r9: merged all three ds levels into ONE 1344-block launch; pool4 folded
// into pre. 8 dispatches -> 5.
// r10: ds kernel had MfmaUtil=0 with two 32x32 GEMMs done on VALU
// (~1024 FMA + ~1024 LDS weight re-reads per thread). pw+qproj now MFMA
// (A=bf16 weights preordered by pre; B=dwconv out staged bf16 [px][40ch]
// in LDS, pad 40 for 2-way banks). BN/SiLU on C-frags fp32; z0 stored
// fp32 from frags; silu'd bf16 written in-place as assembly buffer +
// qproj B operand. Means = 8-val shfl_xor over 16-lane pixel group.
// ---------------------------------------------------------------------------

constexpr int B = 4, C = 32, H = 256, W = 256;
constexpr int HW = H * W;
constexpr int H1 = 128, W1 = 128, HW1 = H1 * W1;
constexpr int H2 = 64,  W2 = 64,  HW2 = H2 * W2;
constexpr int CH = 16;   // head hidden channels
constexpr int CO = 12;   // head output channels
constexpr int TILE = 16;
constexpr int HALO = 18;
constexpr int TAREA = HALO * HALO;   // 324
constexpr int WP = 258;              // padded q edge

typedef unsigned short ushort_t;
typedef __attribute__((ext_vector_type(8))) short bf16x8;
typedef __attribute__((ext_vector_type(4))) float f32x4;
typedef __attribute__((ext_vector_type(2))) float v2f;

static __device__ __forceinline__ float fast_rcp(float x) { return __builtin_amdgcn_rcpf(x); }
static __device__ __forceinline__ float silu_f(float x) { return x * fast_rcp(1.0f + __expf(-x)); }
static __device__ __forceinline__ float tanh_f(float x) {
    float xc = fminf(fmaxf(x, -15.0f), 15.0f);
    float e = __expf(2.0f * xc);
    return (e - 1.0f) * fast_rcp(e + 1.0f);
}
static __device__ __forceinline__ ushort_t f2b(float f) {   // fp32 -> bf16 RNE
    unsigned u = __float_as_uint(f);
    return (ushort_t)((u + 0x7fffu + ((u >> 16) & 1u)) >> 16);
}
static __device__ __forceinline__ float bl(unsigned u) { return __uint_as_float(u << 16); }
static __device__ __forceinline__ float bh(unsigned u) { return __uint_as_float(u & 0xffff0000u); }

// Multi-value butterfly: 8 per-thread channel values -> full-wave sum of
// channel c(lane)=4*b0+2*b1+b2 in lane. 10 shuffles vs 48 for 8 wave_sums.
static __device__ __forceinline__ float red8_ch(float v0, float v1, float v2, float v3,
                                                float v4, float v5, float v6, float v7,
                                                int lane) {
    bool q0 = (lane & 1) != 0, q1 = (lane & 2) != 0, q2 = (lane & 4) != 0;
    float a0 = (q0 ? v4 : v0) + __shfl_xor(q0 ? v0 : v4, 1, 64);
    float a1 = (q0 ? v5 : v1) + __shfl_xor(q0 ? v1 : v5, 1, 64);
    float a2 = (q0 ? v6 : v2) + __shfl_xor(q0 ? v2 : v6, 1, 64);
    float a3 = (q0 ? v7 : v3) + __shfl_xor(q0 ? v3 : v7, 1, 64);
    float c0 = (q1 ? a2 : a0) + __shfl_xor(q1 ? a0 : a2, 2, 64);
    float c1 = (q1 ? a3 : a1) + __shfl_xor(q1 ? a1 : a3, 2, 64);
    float e  = (q2 ? c1 : c0) + __shfl_xor(q2 ? c0 : c1, 4, 64);
    e += __shfl_xor(e, 8, 64);
    e += __shfl_xor(e, 16, 64);
    e += __shfl_xor(e, 32, 64);
    return e;
}

// ---- pre: pool2 + pool4 + qpad border + dall zero + weight reorders -------
__global__ void pre_kernel(const float* __restrict__ x, float* __restrict__ s1,
                           float* __restrict__ s2,
                           ushort_t* __restrict__ qpad, float* __restrict__ dall,
                           const float* __restrict__ h1w1, const float* __restrict__ h2w1,
                           ushort_t* __restrict__ w1ra, ushort_t* __restrict__ w1rb,
                           const float* __restrict__ pw0, const float* __restrict__ pw1,
                           const float* __restrict__ pw2, const float* __restrict__ qw,
                           ushort_t* __restrict__ pwr) {
    int idx = blockIdx.x * blockDim.x + threadIdx.x;
    constexpr int NP = B * C * HW1;
    constexpr int NP2 = B * C * HW2;
    if (idx < NP) {
        int wo = idx % W1; int t = idx / W1;
        int ho = t % H1;   t /= H1;
        const float* src = x + ((size_t)t * H + (size_t)ho * 2) * W + (size_t)wo * 2;
        s1[idx] = (src[0] + src[1] + src[W] + src[W + 1]) * 0.25f;
        return;
    }
    int i = idx - NP;
    if (i < NP2) {                        // s2 = 4x4 mean of x (== avgpool(x,4))
        int wo = i % W2; int t = i / W2;
        int ho = t % H2;   t /= H2;
        const float* src = x + ((size_t)t * H + (size_t)ho * 4) * W + (size_t)wo * 4;
        float s = 0.0f;
#pragma unroll
        for (int r = 0; r < 4; ++r) {
            const float* rp = src + (size_t)r * W;
            s += (rp[0] + rp[1]) + (rp[2] + rp[3]);
        }
        s2[i] = s * 0.0625f;
        return;
    }
    i -= NP2;
    if (i < 4112) {                       // qpad border (4*1028)
        int b = i / 1028, r = i % 1028;
        int y, xx;
        if (r < 258)      { y = 0;           xx = r; }
        else if (r < 516) { y = 257;         xx = r - 258; }
        else if (r < 772) { y = r - 516 + 1; xx = 0; }
        else              { y = r - 772 + 1; xx = 257; }
        uint4 z4 = {0, 0, 0, 0};
        uint4* p = (uint4*)(qpad + (((size_t)b * WP + y) * WP + xx) * 32);
        p[0] = z4; p[1] = z4; p[2] = z4; p[3] = z4;
        return;
    }
    i -= 4112;
    if (i < 512) { dall[i] = 0.0f; return; }
    i -= 512;
    if (i < 4608) {                       // w1ra[o*288 + tap*32 + ci]
        int o = i / 288, k = i - o * 288;
        int j = k >> 5, ci = k & 31;
        w1ra[i] = f2b(h1w1[(o * C + ci) * 9 + j]);
        return;
    }
    i -= 4608;
    if (i < 4608) {
        int o = i / 288, k = i - o * 288;
        int j = k >> 5, ci = k & 31;
        w1rb[i] = f2b(h2w1[(o * C + ci) * 9 + j]);
        return;
    }
    i -= 4608;
    if (i < 4096) {                       // pwr[m][och][inch] bf16 row-major
        int mm = i >> 10, k = i & 1023;
        int o = k >> 5, ci = k & 31;
        const float* wsrc = (mm == 0) ? pw0 : (mm == 1) ? pw1 : (mm == 2) ? pw2 : qw;
        pwr[i] = f2b(wsrc[o * C + ci]);
    }
}

// ---- fused ds_block, all 3 levels in one launch, MFMA pointwise -----------
// blockIdx.x: [0,1024) level0 (z0+qproj+means), [1024,1280) level1 (z1cl),
// [1280,1344) level2 (z2cl).
struct DsParams {
    const float* in; const float* dw;
    const float* g;  const float* b;  const float* m; const float* v;
};

__global__ __launch_bounds__(256, 4) void fused_ds_all_kernel(
        DsParams P0, DsParams P1, DsParams P2, const ushort_t* __restrict__ pwr,
        float* __restrict__ z0out, ushort_t* __restrict__ z1cl,
        ushort_t* __restrict__ z2cl, ushort_t* __restrict__ qout,
        float* __restrict__ dall) {
    // tileu (20736 B) and bstg (256 px * 40 ch bf16 = 20480 B) share space.
    __shared__ __align__(16) char smem[16 * TAREA * 4];
    unsigned* tileu = (unsigned*)smem;
    ushort_t* bstg  = (ushort_t*)smem;
    __shared__ v2f dwp[16 * 9];
    __shared__ __align__(16) float sc[32], sh[32];
    __shared__ float zsum[4][32];

    int bx = blockIdx.x;
    int level = (bx < 1024) ? 0 : (bx < 1280 ? 1 : 2);
    int rel = bx - ((level == 0) ? 0 : (level == 1 ? 1024 : 1280));
    int Hs = (level == 0) ? H : (level == 1 ? H1 : H2);
    int Ws = Hs;
    int tilesX = Ws / TILE;
    int tilesT = tilesX * (Hs / TILE);
    int b = rel / tilesT;
    int tile = rel - b * tilesT;
    int ox = (tile % tilesX) * TILE;
    int oy = (tile / tilesX) * TILE;
    DsParams P = (level == 0) ? P0 : (level == 1 ? P1 : P2);
    int HWs = Hs * Ws;
    int tid = threadIdx.x;
    int lane = tid & 63, wv = tid >> 6;
    int n15 = lane & 15, quad = lane >> 4;
    int tx = tid & 15, ty = tid >> 4;

    for (int i = tid; i < 16 * 9; i += 256) {
        int c2 = i / 9, j = i - c2 * 9;
        dwp[i] = (v2f){P.dw[(2 * c2) * 9 + j], P.dw[(2 * c2 + 1) * 9 + j]};
    }
    if (tid < 32) {
        float s0 = P.g[tid] * rsqrtf(P.v[tid] + 1e-5f);
        sc[tid] = s0;
        sh[tid] = P.b[tid] - P.m[tid] * s0;
    }
    const float* src = P.in + (size_t)b * C * HWs;
    for (int i = tid; i < 16 * TAREA; i += 256) {
        int c2 = i / TAREA, r = i - c2 * TAREA;
        int yy = r / HALO, xx = r - yy * HALO;
        int gy = oy - 1 + yy, gx = ox - 1 + xx;
        float v0 = 0.0f, v1 = 0.0f;
        if (gy >= 0 && gy < Hs && gx >= 0 && gx < Ws) {
            const float* sp = src + (size_t)(2 * c2) * HWs + gy * Ws + gx;
            v0 = sp[0]; v1 = sp[HWs];
        }
        tileu[i] = (unsigned)f2b(v0) | ((unsigned)f2b(v1) << 16);
    }
    __syncthreads();

    // ---- depthwise conv (VALU; per-channel, not matmul-shaped) ----
    int off[9];
#pragma unroll
    for (int jy = 0; jy < 3; ++jy)
#pragma unroll
        for (int jx = 0; jx < 3; ++jx)
            off[jy * 3 + jx] = (ty + jy) * HALO + tx + jx;

    v2f t2[16];
#pragma unroll
    for (int c2 = 0; c2 < 16; ++c2) {
        v2f s = {0.0f, 0.0f};
        const unsigned* tp = tileu + c2 * TAREA;
#pragma unroll
        for (int j = 0; j < 9; ++j) {
            unsigned u = tp[off[j]];
            v2f val = {bl(u), bh(u)};
            s += dwp[c2 * 9 + j] * val;
        }
        t2[c2] = s;
    }
    __syncthreads();   // all dwconv tileu reads done; bstg may overwrite

    // ---- stage dwconv out as bf16 [px][40ch] (pad 40 -> 2-way banks) ----
    {
        unsigned up[16];
#pragma unroll
        for (int j = 0; j < 16; ++j)
            up[j] = (unsigned)f2b(t2[j].x) | ((unsigned)f2b(t2[j].y) << 16);
        uint4* bw = (uint4*)(bstg + (size_t)tid * 40);
#pragma unroll
        for (int j = 0; j < 4; ++j)
            bw[j] = make_uint4(up[4 * j], up[4 * j + 1], up[4 * j + 2], up[4 * j + 3]);
    }
    __syncthreads();

    // ---- MFMA pointwise: A = weights [och 16][inch 32], B = [inch 32][px 16]
    const ushort_t* pwl = pwr + level * 1024;
    bf16x8 apw0 = *(const bf16x8*)(pwl + n15 * 32 + quad * 8);
    bf16x8 apw1 = *(const bf16x8*)(pwl + (16 + n15) * 32 + quad * 8);
    f32x4 c1[4][2];
#pragma unroll
    for (int g4 = 0; g4 < 4; ++g4) {
        bf16x8 bf = *(const bf16x8*)(bstg + ((wv * 4 + g4) * 16 + n15) * 40 + quad * 8);
        f32x4 z = {0.0f, 0.0f, 0.0f, 0.0f};
        c1[g4][0] = __builtin_amdgcn_mfma_f32_16x16x32_bf16(apw0, bf, z, 0, 0, 0);
        c1[g4][1] = __builtin_amdgcn_mfma_f32_16x16x32_bf16(apw1, bf, z, 0, 0, 0);
    }
    // BN + SiLU on C-frags: och = 16*t + 4*quad + r, px = n15 of row wv*4+g4
    f32x4 sc0 = *(const f32x4*)(sc + 4 * quad);
    f32x4 sc1 = *(const f32x4*)(sc + 16 + 4 * quad);
    f32x4 sh0 = *(const f32x4*)(sh + 4 * quad);
    f32x4 sh1 = *(const f32x4*)(sh + 16 + 4 * quad);
#pragma unroll
    for (int g4 = 0; g4 < 4; ++g4)
#pragma unroll
        for (int r = 0; r < 4; ++r) {
            c1[g4][0][r] = silu_f(c1[g4][0][r] * sc0[r] + sh0[r]);
            c1[g4][1][r] = silu_f(c1[g4][1][r] * sc1[r] + sh1[r]);
        }
    __syncthreads();   // all MFMA1 B reads done; overwrite bstg with silu'd

    // silu'd bf16 back in-place: assembly buffer for z1/z2/q + qproj B operand
#pragma unroll
    for (int g4 = 0; g4 < 4; ++g4) {
        int px = (wv * 4 + g4) * 16 + n15;
        unsigned* bp = (unsigned*)(bstg + px * 40 + 4 * quad);
        bp[0] = (unsigned)f2b(c1[g4][0][0]) | ((unsigned)f2b(c1[g4][0][1]) << 16);
        bp[1] = (unsigned)f2b(c1[g4][0][2]) | ((unsigned)f2b(c1[g4][0][3]) << 16);
        unsigned* bp2 = (unsigned*)(bstg + px * 40 + 16 + 4 * quad);
        bp2[0] = (unsigned)f2b(c1[g4][1][0]) | ((unsigned)f2b(c1[g4][1][1]) << 16);
        bp2[1] = (unsigned)f2b(c1[g4][1][2]) | ((unsigned)f2b(c1[g4][1][3]) << 16);
    }
    __syncthreads();

    if (level == 0) {
        // z0 plane-major fp32 straight from frags (no extra rounding)
        float* z0b = z0out + (size_t)b * C * HW;
#pragma unroll
        for (int g4 = 0; g4 < 4; ++g4) {
            float* rp = z0b + (size_t)(oy + wv * 4 + g4) * W + ox + n15;
#pragma unroll
            for (int r = 0; r < 4; ++r) {
                rp[(size_t)(4 * quad + r) * HW]      = c1[g4][0][r];
                rp[(size_t)(16 + 4 * quad + r) * HW] = c1[g4][1][r];
            }
        }
        // channel means: sum 4 rows locally, 4-stage xor over the 16 px lanes
        float ms[8];
#pragma unroll
        for (int r = 0; r < 4; ++r) {
            ms[r]     = (c1[0][0][r] + c1[1][0][r]) + (c1[2][0][r] + c1[3][0][r]);
            ms[4 + r] = (c1[0][1][r] + c1[1][1][r]) + (c1[2][1][r] + c1[3][1][r]);
        }
#pragma unroll
        for (int r = 0; r < 8; ++r) {
            ms[r] += __shfl_xor(ms[r], 1, 64);
            ms[r] += __shfl_xor(ms[r], 2, 64);
            ms[r] += __shfl_xor(ms[r], 4, 64);
            ms[r] += __shfl_xor(ms[r], 8, 64);
        }
        if (n15 == 0) {
#pragma unroll
            for (int r = 0; r < 4; ++r) {
                zsum[wv][4 * quad + r]      = ms[r];
                zsum[wv][16 + 4 * quad + r] = ms[4 + r];
            }
        }
        // qproj MFMA (B = silu'd z0post in bstg)
        const ushort_t* qwl = pwr + 3 * 1024;
        bf16x8 aq0 = *(const bf16x8*)(qwl + n15 * 32 + quad * 8);
        bf16x8 aq1 = *(const bf16x8*)(qwl + (16 + n15) * 32 + quad * 8);
        f32x4 c2[4][2];
#pragma unroll
        for (int g4 = 0; g4 < 4; ++g4) {
            bf16x8 bf = *(const bf16x8*)(bstg + ((wv * 4 + g4) * 16 + n15) * 40 + quad * 8);
            f32x4 z = {0.0f, 0.0f, 0.0f, 0.0f};
            c2[g4][0] = __builtin_amdgcn_mfma_f32_16x16x32_bf16(aq0, bf, z, 0, 0, 0);
            c2[g4][1] = __builtin_amdgcn_mfma_f32_16x16x32_bf16(aq1, bf, z, 0, 0, 0);
        }
        __syncthreads();   // all qproj B reads done; overwrite with q values
#pragma unroll
        for (int g4 = 0; g4 < 4; ++g4) {
            int px = (wv * 4 + g4) * 16 + n15;
            unsigned* bp = (unsigned*)(bstg + px * 40 + 4 * quad);
            bp[0] = (unsigned)f2b(c2[g4][0][0]) | ((unsigned)f2b(c2[g4][0][1]) << 16);
            bp[1] = (unsigned)f2b(c2[g4][0][2]) | ((unsigned)f2b(c2[g4][0][3]) << 16);
            unsigned* bp2 = (unsigned*)(bstg + px * 40 + 16 + 4 * quad);
            bp2[0] = (unsigned)f2b(c2[g4][1][0]) | ((unsigned)f2b(c2[g4][1][1]) << 16);
            bp2[1] = (unsigned)f2b(c2[g4][1][2]) | ((unsigned)f2b(c2[g4][1][3]) << 16);
        }
        __syncthreads();
        // qpad assembly: thread tid owns px tid -> 4 uint4 stores
        const uint4* rb = (const uint4*)(bstg + (size_t)tid * 40);
        uint4 q0 = rb[0], q1 = rb[1], q2 = rb[2], q3 = rb[3];
        uint4* qd = (uint4*)(qout + (((size_t)b * WP + oy + ty + 1) * WP + ox + tx + 1) * 32);
        qd[0] = q0; qd[1] = q1; qd[2] = q2; qd[3] = q3;
        if (tid < 32)
            atomicAdd(&dall[b * 96 + tid],
                      (zsum[0][tid] + zsum[1][tid] + zsum[2][tid] + zsum[3][tid]) * (1.0f / HW));
    } else {
        // z1/z2 channel-last assembly from bstg
        ushort_t* outcl = (level == 1) ? z1cl : z2cl;
        const uint4* rb = (const uint4*)(bstg + (size_t)tid * 40);
        uint4 q0 = rb[0], q1 = rb[1], q2 = rb[2], q3 = rb[3];
        int p = (oy + ty) * Ws + ox + tx;
        uint4* dst = (uint4*)(outcl + ((size_t)b * HWs + p) * C);
        dst[0] = q0; dst[1] = q1; dst[2] = q2; dst[3] = q3;
    }
}

// ---- offsets/weights for one head (halfword offsets into bf16 z) ----------
template<int HC, int WC>
static __device__ __forceinline__ void calc_off(const float* o12, int px, int py,
                                                int* zoff, float* wgt) {
    float mx = fmaxf(fmaxf(o12[8], o12[9]), fmaxf(o12[10], o12[11]));
    float e0 = __expf(o12[8] - mx), e1 = __expf(o12[9] - mx);
    float e2 = __expf(o12[10] - mx), e3 = __expf(o12[11] - mx);
    float inv = fast_rcp(e0 + e1 + e2 + e3);
    float wk4[4] = {e0 * inv, e1 * inv, e2 * inv, e3 * inv};
    float xc = (px + 0.5f) * ((float)WC / (float)W) - 0.5f;
    float yc = (py + 0.5f) * ((float)HC / (float)H) - 0.5f;
#pragma unroll
    for (int k = 0; k < 4; ++k) {
        float ix = fminf(fmaxf(xc + 2.0f * tanh_f(o12[2 * k]),     0.0f), (float)(WC - 1));
        float iy = fminf(fmaxf(yc + 2.0f * tanh_f(o12[2 * k + 1]), 0.0f), (float)(HC - 1));
        float x0f = floorf(ix), y0f = floorf(iy);
        int x0 = (int)x0f, y0 = (int)y0f;
        int x1 = min(x0 + 1, WC - 1), y1 = min(y0 + 1, HC - 1);
        float wx = ix - x0f, wy = iy - y0f;
        float wk = wk4[k];
        zoff[4 * k + 0] = (y0 * WC + x0) * C; wgt[4 * k + 0] = (1.0f - wx) * (1.0f - wy) * wk;
        zoff[4 * k + 1] = (y0 * WC + x1) * C; wgt[4 * k + 1] = wx * (1.0f - wy) * wk;
        zoff[4 * k + 2] = (y1 * WC + x0) * C; wgt[4 * k + 2] = (1.0f - wx) * wy * wk;
        zoff[4 * k + 3] = (y1 * WC + x1) * C; wgt[4 * k + 3] = wx * wy * wk;
    }
}

// ---- one head per block (blockIdx.z): MFMA 3x3 conv + gather tail + means -
// LDS union: q tile (20736 B) is dead after the MFMA loop; hidw (9216 B)
// and ysum (512 B) reuse it -> 20.7 KB/block.
// launch_bounds (256,4): 128-VGPR budget. (256,6) forced 40 VGPR -> scratch
// spill of vv[16]/off/wg (+88MB FETCH, +88MB WRITE). Do NOT lower this.
__global__ __launch_bounds__(256, 4) void head_deform_kernel(
        const ushort_t* __restrict__ qpad,
        const ushort_t* __restrict__ z1, const ushort_t* __restrict__ z2,
        const ushort_t* __restrict__ w1ra, const ushort_t* __restrict__ w1rb,
        const float* __restrict__ w2a, const float* __restrict__ b2a,
        const float* __restrict__ w2b, const float* __restrict__ b2b,
        float* __restrict__ y1, float* __restrict__ y2, float* __restrict__ dall) {
    __shared__ __align__(16) char smem[TAREA * C * 2];      // 20736 B
    ushort_t* tile = (ushort_t*)smem;
    unsigned* hidw = (unsigned*)smem;                       // bytes [0, 9216)
    float (*ysum)[32] = (float (*)[32])(smem + 9216);       // bytes [9216, 9728)
    int tid = threadIdx.x, b = blockIdx.y, hsel = blockIdx.z;
    int ox = (blockIdx.x & 15) * TILE, oy = (blockIdx.x >> 4) * TILE;
    int lane = tid & 63, wv = tid >> 6;
    int n15 = lane & 15, quad = lane >> 4;
    int tx = tid & 15, ty = tid >> 4;

    // stage q tile (rows contiguous in padded channel-last q)
    {
        const ushort_t* base = qpad + ((size_t)b * WP + oy) * WP * 32;
        uint4* tl = (uint4*)tile;
        for (int i = tid; i < 1296; i += 256) {      // 18 rows * 72 16B-chunks
            int yy = i / 72, r = i - yy * 72;
            tl[i] = *(const uint4*)(base + ((size_t)yy * WP + ox) * 32 + r * 8);
        }
    }
    __syncthreads();

    const ushort_t* w1r = hsel ? w1rb : w1ra;
    bf16x8 af[9];
#pragma unroll
    for (int j = 0; j < 9; ++j)
        af[j] = *(const bf16x8*)(w1r + n15 * 288 + j * 32 + quad * 8);
    unsigned pk[8];
#pragma unroll
    for (int g = 0; g < 4; ++g) {
        int yrow = wv * 4 + g;
        f32x4 acc = {0.0f, 0.0f, 0.0f, 0.0f};
#pragma unroll
        for (int jy = 0; jy < 3; ++jy)
#pragma unroll
            for (int jx = 0; jx < 3; ++jx) {
                const bf16x8* bp = (const bf16x8*)(tile +
                    ((yrow + jy) * HALO + n15 + jx) * 32 + quad * 8);
                acc = __builtin_amdgcn_mfma_f32_16x16x32_bf16(
                    af[jy * 3 + jx], *bp, acc, 0, 0, 0);
            }
        pk[2 * g]     = (unsigned)f2b(acc[0]) | ((unsigned)f2b(acc[1]) << 16);
        pk[2 * g + 1] = (unsigned)f2b(acc[2]) | ((unsigned)f2b(acc[3]) << 16);
    }
    __syncthreads();   // ALL waves done reading tile before hidw overwrites it
#pragma unroll
    for (int g = 0; g < 4; ++g) {
        int pxl = (wv * 4 + g) * 16 + n15;
        hidw[pxl * 9 + quad * 2]     = pk[2 * g];
        hidw[pxl * 9 + quad * 2 + 1] = pk[2 * g + 1];
    }
    // hidw write->read is same-wave (pxl in [wv*64, wv*64+64)); lgkmcnt covers it
    float hid[CH];
#pragma unroll
    for (int j = 0; j < 8; ++j) {
        unsigned u = hidw[tid * 9 + j];
        hid[2 * j]     = silu_f(bl(u));
        hid[2 * j + 1] = silu_f(bh(u));
    }

    // ---- tail for this head ----
    const float* w2 = hsel ? w2b : w2a;
    const float* bs = hsel ? b2b : b2a;
    float o12[CO];
#pragma unroll
    for (int j = 0; j < CO; ++j) {
        float a = bs[j];
#pragma unroll
        for (int i = 0; i < CH; ++i) a += w2[j * CH + i] * hid[i];
        o12[j] = a;
    }
    int px = ox + tx, py = oy + ty;
    int off[16]; float wg[16];
    if (hsel == 0) calc_off<H1, W1>(o12, px, py, off, wg);
    else           calc_off<H2, W2>(o12, px, py, off, wg);

    const ushort_t* zb = hsel ? z2 + (size_t)b * HW2 * C : z1 + (size_t)b * HW1 * C;
    int p = py * W + px;
    float* d = (hsel ? y2 : y1) + (size_t)b * C * HW + p;

#pragma unroll
    for (int c8 = 0; c8 < 4; ++c8) {
        uint4 vv[16];
#pragma unroll
        for (int j = 0; j < 16; ++j)
            vv[j] = *(const uint4*)(zb + off[j] + c8 * 8);
        f32x4 lo = {0.0f, 0.0f, 0.0f, 0.0f};
        f32x4 hi = {0.0f, 0.0f, 0.0f, 0.0f};
#pragma unroll
        for (int j = 0; j < 16; ++j) {
            float wj = wg[j];
            lo[0] += wj * bl(vv[j].x); lo[1] += wj * bh(vv[j].x);
            lo[2] += wj * bl(vv[j].y); lo[3] += wj * bh(vv[j].y);
            hi[0] += wj * bl(vv[j].z); hi[1] += wj * bh(vv[j].z);
            hi[2] += wj * bl(vv[j].w); hi[3] += wj * bh(vv[j].w);
        }
#pragma unroll
        for (int k = 0; k < 4; ++k) {
            d[(size_t)(c8 * 8 + k) * HW]     = lo[k];
            d[(size_t)(c8 * 8 + 4 + k) * HW] = hi[k];
        }
        // channel means: butterfly-split reduce (10 shuffles for 8 channels)
        float s = red8_ch(lo[0], lo[1], lo[2], lo[3], hi[0], hi[1], hi[2], hi[3], lane);
        if (lane < 8)
            ysum[wv][c8 * 8 + ((lane & 1) * 4 + (lane & 2) + ((lane >> 2) & 1))] = s;
    }
    __syncthreads();
    if (tid < 32) {
        float s = ysum[0][tid] + ysum[1][tid] + ysum[2][tid] + ysum[3][tid];
        atomicAdd(&dall[b * 96 + 32 + hsel * 32 + tid], s * (1.0f / HW));
    }
}

// ---- gating MLP + softmax -> alpha[B*3] -----------------------------------
__global__ void gate_kernel(const float* __restrict__ dall,
                            const float* __restrict__ w1, const float* __restrict__ b1,
                            const float* __restrict__ w2, const float* __restrict__ b2,
                            float* __restrict__ alpha) {
    __shared__ float hid[B][32];
    int tid = threadIdx.x;
    int b = tid >> 5, j = tid & 31;
    float a = b1[j];
    for (int k = 0; k < 96; ++k) a += dall[b * 96 + k] * w1[k * 32 + j];
    hid[b][j] = silu_f(a);
    __syncthreads();
    if (j == 0) {
        float lg[3];
#pragma unroll
        for (int t = 0; t < 3; ++t) {
            float acc = b2[t];
            for (int jj = 0; jj < 32; ++jj) acc += hid[b][jj] * w2[jj * 3 + t];
            lg[t] = acc;
        }
        float mx = fmaxf(lg[0], fmaxf(lg[1], lg[2]));
        float e0 = __expf(lg[0] - mx), e1 = __expf(lg[1] - mx), e2 = __expf(lg[2] - mx);
        float inv = fast_rcp(e0 + e1 + e2);
        alpha[b * 3 + 0] = e0 * inv;
        alpha[b * 3 + 1] = e1 * inv;
        alpha[b * 3 + 2] = e2 * inv;
    }
}

// ---- fused mix + final 1x1 conv + residual (2 pixels/thread, packed) ------
__global__ __launch_bounds__(256, 4) void final_kernel(
        const float* __restrict__ x,
        const float* __restrict__ z0, const float* __restrict__ y1,
        const float* __restrict__ y2, const float* __restrict__ alpha,
        const float* __restrict__ fw, float* __restrict__ out) {
    __shared__ float ws[C * C];
    for (int i = threadIdx.x; i < C * C; i += blockDim.x) ws[i] = fw[i];
    __syncthreads();
    int idx = blockIdx.x * blockDim.x + threadIdx.x;
    constexpr int HP = HW / 2;
    if (idx >= B * HP) return;
    int b = idx / HP, p = (idx - b * HP) * 2;
    float a0 = alpha[b * 3], a1 = alpha[b * 3 + 1], a2 = alpha[b * 3 + 2];
    size_t base = (size_t)b * C * HW + p;
    v2f mix[C];
#pragma unroll
    for (int i = 0; i < C; ++i) {
        size_t e = base + (size_t)i * HW;
        v2f za = *(const v2f*)(z0 + e);
        v2f ya = *(const v2f*)(y1 + e);
        v2f yb = *(const v2f*)(y2 + e);
        mix[i] = a0 * za + a1 * ya + a2 * yb;
    }
#pragma unroll 4
    for (int o = 0; o < C; ++o) {
        v2f acc = {0.0f, 0.0f};
#pragma unroll
        for (int i = 0; i < C; ++i) acc += ws[o * C + i] * mix[i];
        size_t e = base + (size_t)o * HW;
        v2f xr = *(const v2f*)(x + e);
        *(v2f*)(out + e) = acc + xr;
    }
}

// ---------------------------------------------------------------------------
extern "C" void kernel_launch(void* const* d_in, const int* in_sizes, int n_in,
                              void* d_out, int out_size, void* d_ws, size_t ws_size,
                              hipStream_t stream) {
    const float* x       = (const float*)d_in[0];
    const float* ds_dw[3] = {(const float*)d_in[1],  (const float*)d_in[7],  (const float*)d_in[13]};
    const float* ds_pw[3] = {(const float*)d_in[2],  (const float*)d_in[8],  (const float*)d_in[14]};
    const float* ds_g[3]  = {(const float*)d_in[3],  (const float*)d_in[9],  (const float*)d_in[15]};
    const float* ds_b[3]  = {(const float*)d_in[4],  (const float*)d_in[10], (const float*)d_in[16]};
    const float* ds_m[3]  = {(const float*)d_in[5],  (const float*)d_in[11], (const float*)d_in[17]};
    const float* ds_v[3]  = {(const float*)d_in[6],  (const float*)d_in[12], (const float*)d_in[18]};
    const float* qproj_w = (const float*)d_in[19];
    const float* h1_w1   = (const float*)d_in[20];
    const float* h1_w2   = (const float*)d_in[21];
    const float* h1_b2   = (const float*)d_in[22];
    const float* h2_w1   = (const float*)d_in[23];
    const float* h2_w2   = (const float*)d_in[24];
    const float* h2_b2   = (const float*)d_in[25];
    const float* r_w1    = (const float*)d_in[26];
    const float* r_b1    = (const float*)d_in[27];
    const float* r_w2    = (const float*)d_in[28];
    const float* r_b2    = (const float*)d_in[29];
    const float* final_w = (const float*)d_in[30];
    float* out = (float*)d_out;

    constexpr size_t N0 = (size_t)B * C * HW;
    constexpr size_t N1 = (size_t)B * C * HW1;
    constexpr size_t N2 = (size_t)B * C * HW2;
    constexpr size_t NQ = ((size_t)B * WP * WP * 32 + 1) / 2;   // qpad (u16) in floats

    float* w = (float*)d_ws;
    float* z0   = w; w += N0;      // plane fp32
    float* y1   = w; w += N0;      // plane fp32
    float* y2   = w; w += N0;      // plane fp32
    ushort_t* z1cl = (ushort_t*)w; w += N1 / 2;   // bf16 channel-last
    ushort_t* z2cl = (ushort_t*)w; w += N2 / 2;   // bf16 channel-last
    float* s1   = w; w += N1;
    float* s2   = w; w += N2;
    ushort_t* qpad = (ushort_t*)w; w += NQ;
    ushort_t* w1ra = (ushort_t*)w; w += 2304;   // 4608 bf16
    ushort_t* w1rb = (ushort_t*)w; w += 2304;
    ushort_t* pwr  = (ushort_t*)w; w += 2048;   // 4096 bf16: pw0,pw1,pw2,qw
    float* dall  = w; w += 512;
    float* alpha = w; w += 16;
    (void)ws_size; (void)in_sizes; (void)n_in; (void)out_size;

    const int T = 256;
    auto g = [](size_t n, int t) { return (int)((n + t - 1) / t); };

    pre_kernel<<<g(N1 + N2 + 4112 + 512 + 9216 + 4096, T), T, 0, stream>>>(
        x, s1, s2, qpad, dall, h1_w1, h2_w1, w1ra, w1rb,
        ds_pw[0], ds_pw[1], ds_pw[2], qproj_w, pwr);

    DsParams p0 = {x,  ds_dw[0], ds_g[0], ds_b[0], ds_m[0], ds_v[0]};
    DsParams p1 = {s1, ds_dw[1], ds_g[1], ds_b[1], ds_m[1], ds_v[1]};
    DsParams p2 = {s2, ds_dw[2], ds_g[2], ds_b[2], ds_m[2], ds_v[2]};
    fused_ds_all_kernel<<<1344, T, 0, stream>>>(
        p0, p1, p2, pwr, z0, z1cl, z2cl, qpad, dall);

    head_deform_kernel<<<dim3((H / TILE) * (W / TILE), B, 2), T, 0, stream>>>(
        qpad, z1cl, z2cl, w1ra, w1rb, h1_w2, h1_b2, h2_w2, h2_b2, y1, y2, dall);

    gate_kernel<<<1, 128, 0, stream>>>(dall, r_w1, r_b1, r_w2, r_b2, alpha);

    final_kernel<<<g((size_t)B * HW / 2, T), T, 0, stream>>>(x, z0, y1, y2, alpha, final_w, out);
}